// Round 13
// baseline (691.647 us; speedup 1.0000x reference)
//
#include <hip/hip_runtime.h>
#include <cstdint>
#include <cstddef>

#define NEG_INF (-3.0e38f)

typedef __attribute__((ext_vector_type(8))) short short8;
typedef __attribute__((ext_vector_type(4))) float f32x4;

__device__ inline unsigned short bf16_rne(float x) {
    unsigned u = __float_as_uint(x);
    unsigned r = u + 0x7fffu + ((u >> 16) & 1u);
    return (unsigned short)(r >> 16);
}
__device__ inline float bf16_tof(unsigned short h) {
    return __uint_as_float(((unsigned)h) << 16);
}

// async global->LDS 16B copy: dest must be wave-uniform base + lane*16
__device__ inline void gll16(const void* gsrc, void* ldst) {
    __builtin_amdgcn_global_load_lds(
        (const __attribute__((address_space(1))) unsigned int*)gsrc,
        (__attribute__((address_space(3))) unsigned int*)ldst, 16, 0, 0);
}

// ---------------- prep: normalize keys/hard + bf16 splits ----------------
__global__ void prep_norm_k(const float* __restrict__ keys,
                            const float* __restrict__ hard,
                            float* __restrict__ knR,   // [800][128] normalized keys
                            float* __restrict__ hn,    // [800][128] normalized hard
                            unsigned short* __restrict__ hh,  // [800][128] bf16 hi (norm hard)
                            unsigned short* __restrict__ hl,  // [800][128] bf16 lo (norm hard)
                            unsigned short* __restrict__ hardh,  // [800][128] bf16 hi (raw hard)
                            unsigned short* __restrict__ hardl,  // [800][128] bf16 lo (raw hard)
                            unsigned short* __restrict__ knh,    // [800][128] bf16 hi (norm keys)
                            unsigned short* __restrict__ knl) {  // [800][128] bf16 lo (norm keys)
    int m = blockIdx.x;      // 0..799
    int c = threadIdx.x;     // 0..127
    float kv = keys[m * 128 + c];
    float hv = hard[m * 128 + c];
    __shared__ float s1[128];
    __shared__ float s2[128];
    s1[c] = kv * kv;
    s2[c] = hv * hv;
    __syncthreads();
    for (int off = 64; off > 0; off >>= 1) {
        if (c < off) { s1[c] += s1[c + off]; s2[c] += s2[c + off]; }
        __syncthreads();
    }
    float ks = 1.0f / fmaxf(sqrtf(s1[0]), 1e-12f);
    float hs = 1.0f / fmaxf(sqrtf(s2[0]), 1e-12f);
    float knv = kv * ks;
    knR[m * 128 + c] = knv;
    unsigned short kh = bf16_rne(knv);
    knh[m * 128 + c] = kh;
    knl[m * 128 + c] = bf16_rne(knv - bf16_tof(kh));
    float hnv = hv * hs;
    hn[m * 128 + c] = hnv;
    unsigned short hi = bf16_rne(hnv);
    hh[m * 128 + c] = hi;
    hl[m * 128 + c] = bf16_rne(hnv - bf16_tof(hi));
    unsigned short rh = bf16_rne(hv);
    hardh[m * 128 + c] = rh;
    hardl[m * 128 + c] = bf16_rne(hv - bf16_tof(rh));
}

// prep_c0 emits the bf16 split directly (consumed by fill_c0 granule writes)
__global__ void prep_c0_k(const float* __restrict__ values,
                          unsigned short* __restrict__ c0h,
                          unsigned short* __restrict__ c0l) {
    int c = threadIdx.x;  // 128 threads
    float s = 0.f;
    for (int m = 0; m < 10; ++m) s += values[m * 128 + c];
    s *= 0.1f;
    unsigned short h = bf16_rne(s);
    c0h[c] = h;
    c0l[c] = bf16_rne(s - bf16_tof(h));
}

// ---------------- prep: dec1 weights -> chunked bf16 hi/lo, MFMA A-layout w/ bank swizzle ----------------
__global__ void prep_w1_k(const float* __restrict__ dw1,   // (64,256,3,3)
                          unsigned short* __restrict__ wph,
                          unsigned short* __restrict__ wpl) {
    int idx = blockIdx.x * 256 + threadIdx.x;   // 147456 total
    int co = idx / 2304, r2 = idx % 2304;
    int ci = r2 / 9, tap = r2 % 9;
    float v = dw1[idx];
    int chunk = ci >> 5, cog = co >> 5, co32 = co & 31;
    int cil = ci & 31, g = cil >> 3, j = cil & 7;
    int gs = g ^ ((co32 >> 2) & 3);
    int off = ((((chunk * 9 + tap) * 2 + cog) * 32 + co32) * 4 + gs) * 8 + j;
    unsigned short hi = bf16_rne(v);
    wph[off] = hi;
    wpl[off] = bf16_rne(v - bf16_tof(hi));
}

// ---------------- prep: se2 weights -> triple bf16 split, MFMA A-fragment layout ----------------
__global__ void prep_wse_k(const float* __restrict__ sw2,   // (128,16,3,3)
                           unsigned short* __restrict__ wh,
                           unsigned short* __restrict__ wm,
                           unsigned short* __restrict__ wl) {
    int idx = blockIdx.x * 256 + threadIdx.x;   // 20480 total
    if (idx >= 20480) return;
    int chunk = idx >> 12;
    int rem = idx & 4095;
    int co = rem >> 5;
    int quad = (rem >> 3) & 3;
    int j = rem & 7;
    int tap = chunk * 2 + (quad >> 1);
    int ci = ((quad & 1) << 3) + j;
    float v = (tap < 9) ? sw2[(co * 16 + ci) * 9 + tap] : 0.f;
    unsigned short h = bf16_rne(v);
    float r1 = v - bf16_tof(h);
    unsigned short m_ = bf16_rne(r1);
    float r2 = r1 - bf16_tof(m_);
    wh[idx] = h;
    wm[idx] = m_;
    wl[idx] = bf16_rne(r2);
}

// ---------------- prep: tconv weights -> parity-GEMM A-fragment layout, bf16 hi/lo ----------------
template <int CIN, int COUT>
__global__ void prep_tw(const float* __restrict__ tw,   // (CIN,COUT,4,4)
                        unsigned short* __restrict__ ph,
                        unsigned short* __restrict__ pl) {
    constexpr int GR = CIN / 8;
    constexpr int NKS = CIN / 8;
    int idx = blockIdx.x * 256 + threadIdx.x;
    if (idx >= CIN * COUT * 16) return;
    int j = idx & 7;
    int t1 = idx >> 3;
    int co = t1 % COUT; int t2 = t1 / COUT;
    int quad = t2 & 3; int t3 = t2 >> 2;
    int ks = t3 % NKS; int p = t3 / NKS;
    int kq = ks * 4 + quad;
    int tap = kq / GR, cig = kq % GR;
    int ci = cig * 8 + j;
    int a = tap >> 1, bb = tap & 1;
    int pr = p >> 1, pc = p & 1;
    float v = tw[(((size_t)ci * COUT + co) << 4) + (3 - pr - 2 * a) * 4 + (3 - pc - 2 * bb)];
    unsigned short h = bf16_rne(v);
    ph[idx] = h;
    pl[idx] = bf16_rne(v - bf16_tof(h));
}

// ---------------- center conv1+pool: only pooled rect [45,83)^2 ----------------
__global__ void ce1_k(const float* __restrict__ x,   // (16,1,256,256)
                      const float* __restrict__ w,   // (32,1,3,3)
                      const float* __restrict__ bias,
                      float* __restrict__ out) {     // (16,32,128,128) rect only
    int bx = blockIdx.x;            // 16 b * 2 cog * 6 tiles
    int b = bx / 12, rem = bx % 12;
    int cog = rem / 6, tile = rem % 6;
    int idx = tile * 256 + threadIdx.x;
    if (idx >= 1444) return;
    int ph = 45 + idx / 38, pw = 45 + idx % 38;
    const float* xb = x + (size_t)b * 65536;
    float win[4][4];
#pragma unroll
    for (int r = 0; r < 4; ++r) {
        int ih = 2 * ph - 1 + r;
        bool vr = (ih >= 96 && ih < 160);
#pragma unroll
        for (int c = 0; c < 4; ++c) {
            int iw = 2 * pw - 1 + c;
            win[r][c] = (vr && iw >= 96 && iw < 160) ? xb[ih * 256 + iw] : 0.f;
        }
    }
#pragma unroll
    for (int co8 = 0; co8 < 16; ++co8) {
        int co = cog * 16 + co8;
        const float* w9 = w + co * 9;
        float bv = bias[co];
        float a00 = bv, a01 = bv, a10 = bv, a11 = bv;
#pragma unroll
        for (int kh = 0; kh < 3; ++kh)
#pragma unroll
            for (int kw = 0; kw < 3; ++kw) {
                float wv = w9[kh * 3 + kw];
                a00 += win[kh][kw] * wv;
                a01 += win[kh][kw + 1] * wv;
                a10 += win[kh + 1][kw] * wv;
                a11 += win[kh + 1][kw + 1] * wv;
            }
        float mx = fmaxf(fmaxf(a00, a01), fmaxf(a10, a11));
        out[((size_t)b * 32 + co) * 16384 + ph * 128 + pw] = fmaxf(mx, 0.f);
    }
}

// ---------------- skip conv1+pool: full, 16 co per thread ----------------
__global__ void se1_k(const float* __restrict__ x,   // (16,1,256,256)
                      const float* __restrict__ w,   // (16,1,3,3)
                      const float* __restrict__ bias,
                      float* __restrict__ out) {     // (16,16,128,128)
    int bx = blockIdx.x;            // 16 b * 64 tiles
    int b = bx >> 6, tile = bx & 63;
    int idx = tile * 256 + threadIdx.x;   // 0..16383
    int ph = idx >> 7, pw = idx & 127;
    const float* xb = x + (size_t)b * 65536;
    float win[4][4];
#pragma unroll
    for (int r = 0; r < 4; ++r) {
        int ih = 2 * ph - 1 + r;
        bool vr = (ih >= 0 && ih < 256);
#pragma unroll
        for (int c = 0; c < 4; ++c) {
            int iw = 2 * pw - 1 + c;
            win[r][c] = (vr && iw >= 0 && iw < 256) ? xb[ih * 256 + iw] : 0.f;
        }
    }
#pragma unroll
    for (int co = 0; co < 16; ++co) {
        const float* w9 = w + co * 9;
        float bv = bias[co];
        float a00 = bv, a01 = bv, a10 = bv, a11 = bv;
#pragma unroll
        for (int kh = 0; kh < 3; ++kh)
#pragma unroll
            for (int kw = 0; kw < 3; ++kw) {
                float wv = w9[kh * 3 + kw];
                a00 += win[kh][kw] * wv;
                a01 += win[kh][kw + 1] * wv;
                a10 += win[kh + 1][kw] * wv;
                a11 += win[kh + 1][kw + 1] * wv;
            }
        float mx = fmaxf(fmaxf(a00, a01), fmaxf(a10, a11));
        out[((size_t)b * 16 + co) * 16384 + idx] = fmaxf(mx, 0.f);
    }
}

// ---------------- center conv2 v3 (32->128) + relu + pool -> query-major zcq ----------------
__global__ void __launch_bounds__(256) ce2_v3(
        const float* __restrict__ zc1,  // (16,32,128,128)
        const float* __restrict__ w,    // (128,32,3,3)
        const float* __restrict__ bias,
        float* __restrict__ zcq) {      // (16*324, 128) query-major
    int bx = blockIdx.x;                // 16 b * 16 cog
    int b = bx >> 4, cog = bx & 15;
    const float* ib = zc1 + (size_t)b * 32 * 16384;
    for (int px = threadIdx.x; px < 324; px += 256) {
        int h = 23 + px / 18, ww = 23 + px % 18;
        float acc[8][4];
#pragma unroll
        for (int c8 = 0; c8 < 8; ++c8)
#pragma unroll
            for (int t = 0; t < 4; ++t) acc[c8][t] = 0.f;
        for (int ci = 0; ci < 32; ++ci) {
            const float* p = ib + ci * 16384 + (2 * h - 1) * 128 + (2 * ww - 1);
            float win[4][4];
#pragma unroll
            for (int r = 0; r < 4; ++r)
#pragma unroll
                for (int s = 0; s < 4; ++s) win[r][s] = p[r * 128 + s];
#pragma unroll
            for (int c8 = 0; c8 < 8; ++c8) {
                const float* w9 = w + ((size_t)(cog * 8 + c8) * 32 + ci) * 9;
#pragma unroll
                for (int kh = 0; kh < 3; ++kh)
#pragma unroll
                    for (int kw = 0; kw < 3; ++kw) {
                        float wv = w9[kh * 3 + kw];
                        acc[c8][0] += win[kh][kw] * wv;
                        acc[c8][1] += win[kh][kw + 1] * wv;
                        acc[c8][2] += win[kh + 1][kw] * wv;
                        acc[c8][3] += win[kh + 1][kw + 1] * wv;
                    }
            }
        }
#pragma unroll
        for (int c8 = 0; c8 < 8; ++c8) {
            int co = cog * 8 + c8;
            float mx = fmaxf(fmaxf(acc[c8][0], acc[c8][1]), fmaxf(acc[c8][2], acc[c8][3])) + bias[co];
            zcq[((size_t)(b * 324 + px)) * 128 + co] = fmaxf(mx, 0.f);
        }
    }
}

// ---------------- skip conv2 (16->128) + relu + pool via MFMA, triple bf16 split ----------------
__global__ void __launch_bounds__(256, 2) se2_mfma(
        const float* __restrict__ zs1,   // (16,16,128,128)
        const unsigned short* __restrict__ wh,
        const unsigned short* __restrict__ wm,
        const unsigned short* __restrict__ wl,
        const float* __restrict__ bias,
        float* __restrict__ zs) {        // (16,128,64,64)
    __shared__ unsigned short sm[24960];   // 3 x 8320 shorts (h, m, l)
    int b = blockIdx.x >> 6, pr = blockIdx.x & 63;
    int tid = threadIdx.x;
    int w = tid >> 6, lane = tid & 63;
    int l15 = lane & 15, quad = lane >> 4;

    for (int f = tid; f < 4160; f += 256) {
        int ci2 = f / 520;                 // 0..7 (ci pair index)
        int rem = f - ci2 * 520;
        int wr = rem / 130;
        int col = rem - wr * 130;
        int gr = 2 * pr - 1 + wr;
        int gc = col - 1;
        float v0 = 0.f, v1 = 0.f;
        if (gr >= 0 && gr < 128 && gc >= 0 && gc < 128) {
            const float* p = zs1 + ((size_t)(b * 16 + ci2 * 2) * 128 + gr) * 128 + gc;
            v0 = p[0];
            v1 = p[16384];
        }
        unsigned short h0 = bf16_rne(v0);
        float r0 = v0 - bf16_tof(h0);
        unsigned short m0 = bf16_rne(r0);
        unsigned short l0 = bf16_rne(r0 - bf16_tof(m0));
        unsigned short h1 = bf16_rne(v1);
        float r1 = v1 - bf16_tof(h1);
        unsigned short m1 = bf16_rne(r1);
        unsigned short l1 = bf16_rne(r1 - bf16_tof(m1));
        int off = (((ci2 >> 2) * 4 + wr) * 130 + col) * 8 + ((ci2 & 3) << 1);
        *(unsigned*)&sm[off]         = (unsigned)h0 | ((unsigned)h1 << 16);
        *(unsigned*)&sm[8320 + off]  = (unsigned)m0 | ((unsigned)m1 << 16);
        *(unsigned*)&sm[16640 + off] = (unsigned)l0 | ((unsigned)l1 << 16);
    }
    __syncthreads();

    const unsigned short* xh = sm;
    const unsigned short* xm = sm + 8320;
    const unsigned short* xl = sm + 16640;

    int ct0 = w * 16, ct1 = (w + 4) * 16;   // co bases of this wave's two tiles
    float4 bv0 = *(const float4*)(bias + ct0 + quad * 4);
    float4 bv1 = *(const float4*)(bias + ct1 + quad * 4);

    int th = quad >> 1;
    int cib = quad & 1;

    for (int q = 0; q < 8; ++q) {
        f32x4 acc[2][2];   // [co-tile][conv row]
        acc[0][0] = (f32x4){0.f, 0.f, 0.f, 0.f};
        acc[0][1] = (f32x4){0.f, 0.f, 0.f, 0.f};
        acc[1][0] = (f32x4){0.f, 0.f, 0.f, 0.f};
        acc[1][1] = (f32x4){0.f, 0.f, 0.f, 0.f};
        for (int c = 0; c < 5; ++c) {
            size_t a0 = ((size_t)(c * 128 + ct0 + l15) * 4 + quad) * 8;
            size_t a1 = ((size_t)(c * 128 + ct1 + l15) * 4 + quad) * 8;
            short8 ah0 = *(const short8*)(wh + a0);
            short8 am0 = *(const short8*)(wm + a0);
            short8 al0 = *(const short8*)(wl + a0);
            short8 ah1 = *(const short8*)(wh + a1);
            short8 am1 = *(const short8*)(wm + a1);
            short8 al1 = *(const short8*)(wl + a1);
            int tap = c * 2 + th;
            if (tap > 8) tap = 8;
            int kh = (tap >= 6) ? 2 : ((tap >= 3) ? 1 : 0);
            int kw = tap - kh * 3;
            int bcol = q * 16 + l15 + kw;
#pragma unroll
            for (int rt = 0; rt < 2; ++rt) {
                int boff = ((cib * 4 + rt + kh) * 130 + bcol) * 8;
                short8 bh = *(const short8*)(xh + boff);
                short8 bm = *(const short8*)(xm + boff);
                short8 bl = *(const short8*)(xl + boff);
                {
                    f32x4 a = acc[0][rt];
                    a = __builtin_amdgcn_mfma_f32_16x16x32_bf16(am0, bm, a, 0, 0, 0);
                    a = __builtin_amdgcn_mfma_f32_16x16x32_bf16(al0, bh, a, 0, 0, 0);
                    a = __builtin_amdgcn_mfma_f32_16x16x32_bf16(ah0, bl, a, 0, 0, 0);
                    a = __builtin_amdgcn_mfma_f32_16x16x32_bf16(am0, bh, a, 0, 0, 0);
                    a = __builtin_amdgcn_mfma_f32_16x16x32_bf16(ah0, bm, a, 0, 0, 0);
                    a = __builtin_amdgcn_mfma_f32_16x16x32_bf16(ah0, bh, a, 0, 0, 0);
                    acc[0][rt] = a;
                }
                {
                    f32x4 a = acc[1][rt];
                    a = __builtin_amdgcn_mfma_f32_16x16x32_bf16(am1, bm, a, 0, 0, 0);
                    a = __builtin_amdgcn_mfma_f32_16x16x32_bf16(al1, bh, a, 0, 0, 0);
                    a = __builtin_amdgcn_mfma_f32_16x16x32_bf16(ah1, bl, a, 0, 0, 0);
                    a = __builtin_amdgcn_mfma_f32_16x16x32_bf16(am1, bh, a, 0, 0, 0);
                    a = __builtin_amdgcn_mfma_f32_16x16x32_bf16(ah1, bm, a, 0, 0, 0);
                    a = __builtin_amdgcn_mfma_f32_16x16x32_bf16(ah1, bh, a, 0, 0, 0);
                    acc[1][rt] = a;
                }
            }
        }
        int pc = q * 8 + (l15 >> 1);
#pragma unroll
        for (int t = 0; t < 2; ++t) {
            int cbase = (t ? ct1 : ct0) + quad * 4;
            float4 bv = t ? bv1 : bv0;
#pragma unroll
            for (int u = 0; u < 4; ++u) {
                float pm = fmaxf(acc[t][0][u], acc[t][1][u]);
                pm = fmaxf(pm, __shfl_xor(pm, 1));
                if ((lane & 1) == 0) {
                    float bb = (u == 0) ? bv.x : (u == 1) ? bv.y : (u == 2) ? bv.z : bv.w;
                    zs[((size_t)(b * 128 + cbase + u)) * 4096 + pr * 64 + pc] = fmaxf(pm + bb, 0.f);
                }
            }
        }
    }
}

// ---------------- center matching v3: MFMA sims (keys direct from L2), LDS scoreboard ----------------
__global__ void __launch_bounds__(256, 2) match_center_v3(
        const float* __restrict__ zcq,    // (16*324, 128) raw queries
        const float* __restrict__ knR,    // (800,128) normalized keys fp32 (rescue)
        const unsigned short* __restrict__ knh,  // (800,128) bf16 hi
        const unsigned short* __restrict__ knl,  // (800,128) bf16 lo
        const float* __restrict__ values, // (800,128)
        unsigned short* __restrict__ dchh, // [16][32][4096][8] ch 0..127 -> G 0..15
        unsigned short* __restrict__ dchl) {
    __shared__ __align__(16) float scores[16 * 804];   // 51456 B
    __shared__ __align__(16) float qint[16 * 132];     // 8448 B
    int tid = threadIdx.x;
    int w = tid >> 6, lane = tid & 63;
    int l15 = lane & 15, quad = lane >> 4;
    int qbase = blockIdx.x * 16;

    const float* qp = zcq + (size_t)(qbase + l15) * 128;
    float qv[4][8];
    float ss = 0.f;
#pragma unroll
    for (int ks = 0; ks < 4; ++ks) {
        int c0 = (ks * 4 + quad) * 8;
        float4 a = *(const float4*)(qp + c0);
        float4 bq = *(const float4*)(qp + c0 + 4);
        qv[ks][0] = a.x; qv[ks][1] = a.y; qv[ks][2] = a.z; qv[ks][3] = a.w;
        qv[ks][4] = bq.x; qv[ks][5] = bq.y; qv[ks][6] = bq.z; qv[ks][7] = bq.w;
#pragma unroll
        for (int j = 0; j < 8; ++j) ss += qv[ks][j] * qv[ks][j];
    }
    ss += __shfl_xor(ss, 16);
    ss += __shfl_xor(ss, 32);
    float sc = 1.0f / fmaxf(sqrtf(ss), 1e-12f);
    short8 ahi[4], alo[4];
#pragma unroll
    for (int ks = 0; ks < 4; ++ks) {
#pragma unroll
        for (int j = 0; j < 8; ++j) {
            float v = qv[ks][j] * sc;
            qv[ks][j] = v;
            unsigned short h = bf16_rne(v);
            ahi[ks][j] = (short)h;
            alo[ks][j] = (short)bf16_rne(v - bf16_tof(h));
        }
    }
    if (w == 0) {
#pragma unroll
        for (int ks = 0; ks < 4; ++ks) {
            int c0 = (ks * 4 + quad) * 8;
            *(float4*)(qint + l15 * 132 + c0) =
                make_float4(qv[ks][0], qv[ks][1], qv[ks][2], qv[ks][3]);
            *(float4*)(qint + l15 * 132 + c0 + 4) =
                make_float4(qv[ks][4], qv[ks][5], qv[ks][6], qv[ks][7]);
        }
    }

    for (int kt = w; kt < 50; kt += 4) {
        f32x4 acc = (f32x4){0.f, 0.f, 0.f, 0.f};
#pragma unroll
        for (int ks = 0; ks < 4; ++ks) {
            size_t koff = ((size_t)(kt * 16 + l15) * 128) + (size_t)((ks * 4 + quad) * 8);
            short8 bhi = *(const short8*)(knh + koff);
            short8 blo = *(const short8*)(knl + koff);
            acc = __builtin_amdgcn_mfma_f32_16x16x32_bf16(alo[ks], bhi, acc, 0, 0, 0);
            acc = __builtin_amdgcn_mfma_f32_16x16x32_bf16(ahi[ks], blo, acc, 0, 0, 0);
            acc = __builtin_amdgcn_mfma_f32_16x16x32_bf16(ahi[ks], bhi, acc, 0, 0, 0);
        }
#pragma unroll
        for (int u = 0; u < 4; ++u)
            scores[(quad * 4 + u) * 804 + kt * 16 + l15] = acc[u];
    }
    __syncthreads();

    for (int qi = 0; qi < 4; ++qi) {
        int q = w * 4 + qi;
        int g = qbase + q;
        int b = g / 324, qq = g - b * 324;
        int h = 23 + qq / 18, ww2 = 23 + qq % 18;
        int p = h * 64 + ww2;

        float sim[13];
#pragma unroll
        for (int k = 0; k < 13; ++k)
            sim[k] = (lane + (k << 6) < 800) ? scores[q * 804 + lane + (k << 6)] : NEG_INF;

        float topv[11]; int topm[11];
#pragma unroll
        for (int t = 0; t < 11; ++t) {
            float bvv = NEG_INF; int bm = 0x7fffffff;
#pragma unroll
            for (int k = 0; k < 13; ++k) {
                if (sim[k] > bvv) { bvv = sim[k]; bm = lane + (k << 6); }
            }
#pragma unroll
            for (int off = 32; off > 0; off >>= 1) {
                float ov = __shfl_xor(bvv, off);
                int om = __shfl_xor(bm, off);
                if (ov > bvv || (ov == bvv && om < bm)) { bvv = ov; bm = om; }
            }
            topv[t] = bvv; topm[t] = bm;
            if ((bm & 63) == lane) {
                int kk = bm >> 6;
#pragma unroll
                for (int k = 0; k < 13; ++k)
                    if (k == kk) sim[k] = NEG_INF;
            }
        }
        if (topv[9] - topv[10] < 1e-4f) {
            double s9 = 0.0, s10 = 0.0;
            const float* k9 = knR + (size_t)topm[9] * 128;
            const float* k10 = knR + (size_t)topm[10] * 128;
            for (int c = 0; c < 128; ++c) {
                double qc = (double)qint[q * 132 + c];
                s9 += qc * (double)k9[c];
                s10 += qc * (double)k10[c];
            }
            if ((s10 > s9) || (s10 == s9 && topm[10] < topm[9])) {
                topv[9] = topv[10]; topm[9] = topm[10];
            }
        }
        float mx = topv[0];
        float e[10], ssum = 0.f;
#pragma unroll
        for (int t = 0; t < 10; ++t) { e[t] = expf(topv[t] - mx); ssum += e[t]; }
        float inv = 1.0f / ssum;
        float o0 = 0.f, o1 = 0.f;
#pragma unroll
        for (int t = 0; t < 10; ++t) {
            float wt = e[t] * inv;
            const float* vr = values + (size_t)topm[t] * 128;
            o0 += wt * vr[lane];
            o1 += wt * vr[lane + 64];
        }
        unsigned short h0 = bf16_rne(o0);
        unsigned short l0 = bf16_rne(o0 - bf16_tof(h0));
        unsigned short h1 = bf16_rne(o1);
        unsigned short l1 = bf16_rne(o1 - bf16_tof(h1));
        size_t a0 = ((size_t)(b * 32 + (lane >> 3)) * 4096 + p) * 8 + (lane & 7);
        size_t a1 = ((size_t)(b * 32 + 8 + (lane >> 3)) * 4096 + p) * 8 + (lane & 7);
        dchh[a0] = h0; dchl[a0] = l0;
        dchh[a1] = h1; dchl[a1] = l1;
    }
}

// ---------------- constant fill for out-of-region center matches (granule writes) ----------------
__global__ void fill_c0_k(const unsigned short* __restrict__ c0h,
                          const unsigned short* __restrict__ c0l,
                          unsigned short* __restrict__ dchh,
                          unsigned short* __restrict__ dchl) {
    int idx = blockIdx.x * 256 + threadIdx.x;  // 16b * 16G * 4096p = 1048576
    int p = idx & 4095;
    int G = (idx >> 12) & 15;
    int b = idx >> 16;
    int h = p >> 6, ww = p & 63;
    if (h >= 23 && h <= 40 && ww >= 23 && ww <= 40) return;
    uint4 vh = *(const uint4*)(c0h + G * 8);
    uint4 vl = *(const uint4*)(c0l + G * 8);
    size_t off = ((size_t)(b * 32 + G) * 4096 + p) * 8;
    *(uint4*)(dchh + off) = vh;
    *(uint4*)(dchl + off) = vl;
}

// ---------------- skip matching v8: keys direct from L2 (no staging, no in-loop barriers) ----------------
// R23: v7 (~78us) was barrier-lockstepped: 25 chunks x dbuf gll16 staging of L2-resident keys.
// Keys (hh/hl, 400KB) are L2-hot across 1024 blocks -> read B-frags directly global->reg
// (match_center_v3 pattern). Zero in-loop barriers; latency hidden by TLP (4 blk/CU).
// Same accumulation order -> bit-identical scores; selection/rescore/copy-out unchanged.
__global__ void __launch_bounds__(256, 4) match_skip_v8(
        const float* __restrict__ zs,    // (16,128,64,64) raw queries
        const float* __restrict__ hn,    // (800,128) normalized fp32 (rescore)
        const unsigned short* __restrict__ hh,  // (800,128) bf16 hi
        const unsigned short* __restrict__ hl,  // (800,128) bf16 lo
        const unsigned short* __restrict__ hardh,  // (800,128) raw bf16 hi
        const unsigned short* __restrict__ hardl,  // (800,128) raw bf16 lo
        unsigned short* __restrict__ dchh,  // G 16..31 (ch 128..255)
        unsigned short* __restrict__ dchl) {
    __shared__ __align__(16) float4 red[64 * 17];   // 17408 B
    __shared__ float qn2s[64];
    __shared__ int bi_sh[64];
    int b = blockIdx.x >> 6, pt = blockIdx.x & 63;
    int pbase = pt * 64;
    int tid = threadIdx.x;
    int w = tid >> 6, lane = tid & 63;
    int l15 = lane & 15, quad = lane >> 4;

    // query A-frags -> registers (hi/lo split identical to v7) + qn2
    int qrow = 16 * w + l15;
    const float* zq = zs + ((size_t)b * 128) * 4096 + pbase + qrow;
    short8 ahi[4], alo[4];
    float qn2p = 0.f;
#pragma unroll
    for (int ks = 0; ks < 4; ++ks) {
        int cb = ks * 4 + quad;
#pragma unroll
        for (int j = 0; j < 8; ++j) {
            float v = zq[(size_t)(cb * 8 + j) * 4096];
            unsigned short h = bf16_rne(v);
            ahi[ks][j] = (short)h;
            alo[ks][j] = (short)bf16_rne(v - bf16_tof(h));
            qn2p += v * v;
        }
    }
    qn2p += __shfl_xor(qn2p, 16);
    qn2p += __shfl_xor(qn2p, 32);
    if (quad == 0) qn2s[16 * w + l15] = qn2p;

    float v1[4], v2[4]; int i1[4], i2[4];
#pragma unroll
    for (int u = 0; u < 4; ++u) { v1[u] = NEG_INF; v2[u] = NEG_INF; i1[u] = 0x7fffffff; i2[u] = 0x7fffffff; }

    for (int c = 0; c < 25; ++c) {
        f32x4 acc[2];
        acc[0] = (f32x4){0.f, 0.f, 0.f, 0.f};
        acc[1] = (f32x4){0.f, 0.f, 0.f, 0.f};
#pragma unroll
        for (int ks = 0; ks < 4; ++ks) {
            int cb = ks * 4 + quad;
#pragma unroll
            for (int kt = 0; kt < 2; ++kt) {
                int gm = c * 32 + kt * 16 + l15;     // < 800 always (800 = 25*32)
                size_t koff = (size_t)gm * 128 + (size_t)(cb * 8);
                short8 bhi = *(const short8*)(hh + koff);
                short8 blo = *(const short8*)(hl + koff);
                acc[kt] = __builtin_amdgcn_mfma_f32_16x16x32_bf16(alo[ks], bhi, acc[kt], 0, 0, 0);
                acc[kt] = __builtin_amdgcn_mfma_f32_16x16x32_bf16(ahi[ks], blo, acc[kt], 0, 0, 0);
                acc[kt] = __builtin_amdgcn_mfma_f32_16x16x32_bf16(ahi[ks], bhi, acc[kt], 0, 0, 0);
            }
        }
        int mb = c * 32;
#pragma unroll
        for (int kt = 0; kt < 2; ++kt) {
            int m = mb + 16 * kt + l15;
#pragma unroll
            for (int u = 0; u < 4; ++u) {
                float sv = acc[kt][u];
                bool b1 = sv > v1[u];
                bool b2 = sv > v2[u];
                float nv2 = b1 ? v1[u] : (b2 ? sv : v2[u]);
                int   ni2 = b1 ? i1[u] : (b2 ? m : i2[u]);
                v1[u] = b1 ? sv : v1[u];
                i1[u] = b1 ? m : i1[u];
                v2[u] = nv2; i2[u] = ni2;
            }
        }
    }

#pragma unroll
    for (int u = 0; u < 4; ++u) {
        int q = 16 * w + quad * 4 + u;
        red[q * 17 + l15] = make_float4(v1[u], v2[u], __int_as_float(i1[u]), __int_as_float(i2[u]));
    }
    __syncthreads();
    if (tid < 64) {
        int q = tid;
        float V1 = NEG_INF; int I1 = 0x7fffffff;
        for (int k = 0; k < 16; ++k) {
            float4 e = red[q * 17 + k];
            float cv[2] = { e.x, e.y };
            int ci_[2] = { __float_as_int(e.z), __float_as_int(e.w) };
#pragma unroll
            for (int t = 0; t < 2; ++t) {
                if (cv[t] > V1 || (cv[t] == V1 && ci_[t] < I1)) { V1 = cv[t]; I1 = ci_[t]; }
            }
        }
        float tau = 1.5e-4f * sqrtf(qn2s[q]) + 1e-12f;
        float thr = V1 - tau;
        int ncand = 0;
        for (int k = 0; k < 16; ++k) {
            float4 e = red[q * 17 + k];
            if (e.x >= thr && __float_as_int(e.z) != 0x7fffffff) ++ncand;
            if (e.y >= thr && __float_as_int(e.w) != 0x7fffffff) ++ncand;
        }
        int bi = I1;
        if (ncand > 1) {
            double bestd = -1.0e300; int besti = 0x7fffffff;
            for (int k = 0; k < 16; ++k) {
                float4 e = red[q * 17 + k];
                float cv[2] = { e.x, e.y };
                int ci_[2] = { __float_as_int(e.z), __float_as_int(e.w) };
                for (int t = 0; t < 2; ++t) {
                    if (cv[t] >= thr && ci_[t] != 0x7fffffff) {
                        const float* hr = hn + (size_t)ci_[t] * 128;
                        double d = 0.0;
                        for (int c = 0; c < 128; ++c) {
                            double qc = (double)zs[((size_t)b * 128 + c) * 4096 + pbase + q];
                            d += qc * (double)hr[c];
                        }
                        if (d > bestd || (d == bestd && ci_[t] < besti)) { bestd = d; besti = ci_[t]; }
                    }
                }
            }
            bi = besti;
        }
        bi_sh[q] = bi;
    }
    __syncthreads();
    {
        int q = tid & 63, seg = tid >> 6;
        int bi = bi_sh[q];
        const unsigned short* hhr = hardh + (size_t)bi * 128;
        const unsigned short* hlr = hardl + (size_t)bi * 128;
        size_t pb = (size_t)pbase + q;
#pragma unroll
        for (int gi = 0; gi < 4; ++gi) {
            int cb = seg * 32 + gi * 8;          // 0..127 within skip half
            int G = 16 + (cb >> 3);              // global granule 16..31
            uint4 vh = *(const uint4*)(hhr + cb);
            uint4 vl = *(const uint4*)(hlr + cb);
            size_t off = ((size_t)(b * 32 + G) * 4096 + pb) * 8;
            *(uint4*)(dchh + off) = vh;
            *(uint4*)(dchl + off) = vl;
        }
    }
}

// ---------------- decoder conv1 v14: v11 structure + XCD-pairing block swizzle ----------------
__global__ void __launch_bounds__(256, 2) dec1_v14(
        const unsigned short* __restrict__ dch,  // hi granules [16][32][4096][8]
        const unsigned short* __restrict__ dcl,  // lo granules
        const unsigned short* __restrict__ wph,  // prepped weights hi
        const unsigned short* __restrict__ wpl,  // prepped weights lo
        const float* __restrict__ bias,
        unsigned short* __restrict__ d1gh,  // out granules [16][8][4096][8]
        unsigned short* __restrict__ d1gl) {
    __shared__ unsigned short smem[31104];  // x: hi [0,6336), lo [6336,12672); w: [12672,31104)
    int bxh = blockIdx.x;               // hardware index 0..2047
    int grp = bxh >> 4, rem16 = bxh & 15;
    int cog = rem16 >> 3, sub = rem16 & 7;
    int li = grp * 8 + sub;             // logical (b,r0) 0..1023
    int b = li >> 6, r0 = li & 63;
    int tid = threadIdx.x;
    int w = tid >> 6, lane = tid & 63;
    int l15 = lane & 15, quad = lane >> 4;
    int mt = w & 1, nh = w >> 1;
    int gx = quad ^ ((l15 >> 2) & 3);

    {
        uint4 z = make_uint4(0u, 0u, 0u, 0u);
        for (int f = tid; f < 1584; f += 256)
            *(uint4*)&smem[f * 8] = z;
    }

    bool vld[3];
    int gof[3], lof[3];
#pragma unroll
    for (int k = 0; k < 3; ++k) {
        int gr = r0 - 1 + k;
        vld[k] = (gr >= 0 && gr < 64);          // block-uniform
        gof[k] = ((b * 32 + w) * 4096 + gr * 64 + lane) * 8;
        lof[k] = ((k * 4 + w) * 66 + lane + 1) * 8;
    }
    __syncthreads();

#pragma unroll
    for (int k = 0; k < 3; ++k)
        if (vld[k]) {
            gll16(dch + gof[k], &smem[lof[k]]);
            gll16(dcl + gof[k], &smem[6336 + lof[k]]);
        }
#pragma unroll
    for (int k = 0; k < 5; ++k) {
        int t = tid + k * 256;
        if (t < 1152) {
            int tap = t >> 7, wi = t & 127;
            size_t src = ((size_t)((0 * 9 + tap) * 2 + cog)) * 1024 + wi * 8;
            int dst = 12672 + tap * 1024 + wi * 8;
            gll16(wph + src, &smem[dst]);
            gll16(wpl + src, &smem[dst + 9216]);
        }
    }
    __syncthreads();

    f32x4 acc[2];
    acc[0] = (f32x4){0.f, 0.f, 0.f, 0.f};
    acc[1] = (f32x4){0.f, 0.f, 0.f, 0.f};

    for (int chunk = 0; chunk < 8; ++chunk) {
#pragma unroll
        for (int tap = 0; tap < 9; ++tap) {
            int kh = tap / 3, kw = tap % 3;
            int aoff = 12672 + tap * 1024 + (mt * 16 + l15) * 32 + gx * 8;
            short8 ahi = *(const short8*)&smem[aoff];
            short8 alo = *(const short8*)&smem[aoff + 9216];
#pragma unroll
            for (int n2 = 0; n2 < 2; ++n2) {
                int nt = nh * 2 + n2;
                int boff = ((kh * 4 + quad) * 66 + nt * 16 + l15 + kw) * 8;
                short8 bhi = *(const short8*)&smem[boff];
                short8 blo = *(const short8*)&smem[boff + 6336];
                acc[n2] = __builtin_amdgcn_mfma_f32_16x16x32_bf16(alo, bhi, acc[n2], 0, 0, 0);
                acc[n2] = __builtin_amdgcn_mfma_f32_16x16x32_bf16(ahi, blo, acc[n2], 0, 0, 0);
                acc[n2] = __builtin_amdgcn_mfma_f32_16x16x32_bf16(ahi, bhi, acc[n2], 0, 0, 0);
            }
        }
        if (chunk < 7) {
            __syncthreads();
            int coff = (chunk + 1) * 131072;
#pragma unroll
            for (int k = 0; k < 3; ++k)
                if (vld[k]) {
                    gll16(dch + gof[k] + coff, &smem[lof[k]]);
                    gll16(dcl + gof[k] + coff, &smem[6336 + lof[k]]);
                }
#pragma unroll
            for (int k = 0; k < 5; ++k) {
                int t = tid + k * 256;
                if (t < 1152) {
                    int tap = t >> 7, wi = t & 127;
                    size_t src = ((size_t)(((chunk + 1) * 9 + tap) * 2 + cog)) * 1024 + wi * 8;
                    int dst = 12672 + tap * 1024 + wi * 8;
                    gll16(wph + src, &smem[dst]);
                    gll16(wpl + src, &smem[dst + 9216]);
                }
            }
            __syncthreads();
        }
    }
    int co0 = cog * 32 + mt * 16 + quad * 4;
    int G = co0 >> 3, j0 = co0 & 7;
    float4 bv = *(const float4*)(bias + co0);
#pragma unroll
    for (int n2 = 0; n2 < 2; ++n2) {
        int nt = nh * 2 + n2;
        int px = r0 * 64 + nt * 16 + l15;
        float v0 = fmaxf(acc[n2][0] + bv.x, 0.f);
        float v1 = fmaxf(acc[n2][1] + bv.y, 0.f);
        float v2 = fmaxf(acc[n2][2] + bv.z, 0.f);
        float v3 = fmaxf(acc[n2][3] + bv.w, 0.f);
        unsigned short h0 = bf16_rne(v0), h1 = bf16_rne(v1), h2 = bf16_rne(v2), h3 = bf16_rne(v3);
        unsigned short l0 = bf16_rne(v0 - bf16_tof(h0)), l1 = bf16_rne(v1 - bf16_tof(h1));
        unsigned short l2 = bf16_rne(v2 - bf16_tof(h2)), l3 = bf16_rne(v3 - bf16_tof(h3));
        size_t off = ((size_t)(b * 8 + G) * 4096 + px) * 8 + j0;
        *(uint2*)(d1gh + off) = make_uint2((unsigned)h0 | ((unsigned)h1 << 16),
                                           (unsigned)h2 | ((unsigned)h3 << 16));
        *(uint2*)(d1gl + off) = make_uint2((unsigned)l0 | ((unsigned)l1 << 16),
                                           (unsigned)l2 | ((unsigned)l3 << 16));
    }
}

// ---------------- transposed conv via MFMA: 4 parity GEMMs, granule input, gll16 staging ----------
template <int CIN, int COUT, int H, bool WIDE, bool GRANOUT>
__global__ void __launch_bounds__(256) tconv_m(
        const unsigned short* __restrict__ xgh,  // [16][CIN/8][H][H][8]
        const unsigned short* __restrict__ xgl,
        const unsigned short* __restrict__ wth,  // [4][NKS][4][COUT][8]
        const unsigned short* __restrict__ wtl,
        const float* __restrict__ bias,
        float* __restrict__ outf,                // (16,COUT,2H,2H) if !GRANOUT
        unsigned short* __restrict__ goh,        // [16][COUT/8][2H][2H][8] if GRANOUT
        unsigned short* __restrict__ gol) {
    constexpr int GR = CIN / 8;
    constexpr int NKS = CIN / 8;
    constexpr int COLS = H + 2;
    constexpr int XSZ = 3 * GR * COLS * 8;
    __shared__ __align__(16) unsigned short sm[2 * XSZ];
    int b = blockIdx.x / H, i = blockIdx.x % H;
    int tid = threadIdx.x, w = tid >> 6, lane = tid & 63;
    int l15 = lane & 15, quad = lane >> 4;

    {
        uint4 z = make_uint4(0u, 0u, 0u, 0u);
        for (int f = tid; f < (2 * XSZ) / 8; f += 256) *(uint4*)&sm[f * 8] = z;
    }
    __syncthreads();
    for (int t = w; t < 3 * GR * (WIDE ? 2 : 1); t += 4) {
        int r, g, ch;
        if (WIDE) { r = t >> 3; int s = t & 7; g = s >> 1; ch = s & 1; }
        else      { r = t / GR; g = t % GR; ch = 0; }
        int rg = i - 1 + r;
        if (rg >= 0 && rg < H) {   // wave-uniform
            int col = ch * 64 + lane;
            int dst = ((r * GR + g) * COLS + col + 1) * 8;
            size_t src = ((size_t)((b * GR + g) * H + rg) * H + col) * 8;
            gll16(xgh + src, &sm[dst]);
            gll16(xgl + src, &sm[XSZ + dst]);
        }
    }
    __syncthreads();

    int pr = w >> 1;
    int wh2 = WIDE ? (w & 1) : 0;
    int mt = WIDE ? 0 : (w & 1);
    int co0 = mt * 16 + quad * 4;
    float4 bv = *(const float4*)(bias + co0);

    for (int pc = 0; pc < 2; ++pc) {
        int p = pr * 2 + pc;
        f32x4 acc[4];
#pragma unroll
        for (int nt = 0; nt < 4; ++nt) acc[nt] = (f32x4){0.f, 0.f, 0.f, 0.f};
#pragma unroll
        for (int ks = 0; ks < NKS; ++ks) {
            size_t aoff = ((size_t)(((p * NKS + ks) * 4 + quad) * COUT) + mt * 16 + l15) * 8;
            short8 ahi = *(const short8*)(wth + aoff);
            short8 alo = *(const short8*)(wtl + aoff);
            int kq = ks * 4 + quad;
            int tap = kq / GR, cig = kq % GR;
            int irow = pr + (tap >> 1);
            int cadd = pc + (tap & 1);
#pragma unroll
            for (int nt = 0; nt < 4; ++nt) {
                int jcol = (wh2 * 4 + nt) * 16 + l15;
                int boff = ((irow * GR + cig) * COLS + jcol + cadd) * 8;
                short8 bhi = *(const short8*)&sm[boff];
                short8 blo = *(const short8*)&sm[XSZ + boff];
                acc[nt] = __builtin_amdgcn_mfma_f32_16x16x32_bf16(alo, bhi, acc[nt], 0, 0, 0);
                acc[nt] = __builtin_amdgcn_mfma_f32_16x16x32_bf16(ahi, blo, acc[nt], 0, 0, 0);
                acc[nt] = __builtin_amdgcn_mfma_f32_16x16x32_bf16(ahi, bhi, acc[nt], 0, 0, 0);
            }
        }
#pragma unroll
        for (int nt = 0; nt < 4; ++nt) {
            int jcol = (wh2 * 4 + nt) * 16 + l15;
            int orow = 2 * i + pr, ocol = 2 * jcol + pc;
            float v0 = fmaxf(acc[nt][0] + bv.x, 0.f);
            float v1 = fmaxf(acc[nt][1] + bv.y, 0.f);
            float v2 = fmaxf(acc[nt][2] + bv.z, 0.f);
            float v3 = fmaxf(acc[nt][3] + bv.w, 0.f);
            if constexpr (GRANOUT) {
                unsigned short h0 = bf16_rne(v0), h1 = bf16_rne(v1), h2 = bf16_rne(v2), h3 = bf16_rne(v3);
                unsigned short q0 = bf16_rne(v0 - bf16_tof(h0)), q1 = bf16_rne(v1 - bf16_tof(h1));
                unsigned short q2 = bf16_rne(v2 - bf16_tof(h2)), q3 = bf16_rne(v3 - bf16_tof(h3));
                int G = co0 >> 3, j0 = co0 & 7;
                size_t off = ((size_t)((b * (COUT / 8) + G) * (2 * H) + orow) * (2 * H) + ocol) * 8 + j0;
                *(uint2*)(goh + off) = make_uint2((unsigned)h0 | ((unsigned)h1 << 16),
                                                  (unsigned)h2 | ((unsigned)h3 << 16));
                *(uint2*)(gol + off) = make_uint2((unsigned)q0 | ((unsigned)q1 << 16),
                                                  (unsigned)q2 | ((unsigned)q3 << 16));
            } else {
                size_t ob = ((size_t)(b * COUT + co0) * (2 * H) + orow) * (2 * H) + ocol;
                constexpr size_t CS = (size_t)4 * H * H;
                outf[ob] = v0;
                outf[ob + CS] = v1;
                outf[ob + 2 * CS] = v2;
                outf[ob + 3 * CS] = v3;
            }
        }
    }
}

// ---------------- final conv (16->1) 3x3, 4 px per thread ----------------
__global__ void final_v2(const float* __restrict__ t2,  // (16,16,256,256)
                         const float* __restrict__ w,   // (1,16,3,3)
                         const float* __restrict__ bias,
                         float* __restrict__ out) {     // (16,1,256,256)
    int g = blockIdx.x * 256 + threadIdx.x;
    int pxb = g * 4;
    int b = pxb >> 16, p = pxb & 65535;
    int h = p >> 8, c0 = p & 255;
    const float* tb = t2 + (size_t)b * 16 * 65536;
    float acc[4];
    float bv = bias[0];
#pragma unroll
    for (int t = 0; t < 4; ++t) acc[t] = bv;
    for (int ci = 0; ci < 16; ++ci) {
        const float* pp = tb + (size_t)ci * 65536;
        const float* w9 = w + ci * 9;
        float win[3][6];
#pragma unroll
        for (int dr = 0; dr < 3; ++dr) {
            int rr = h - 1 + dr;
            bool vr = (rr >= 0 && rr < 256);
#pragma unroll
            for (int dc = 0; dc < 6; ++dc) {
                int cc = c0 - 1 + dc;
                win[dr][dc] = (vr && cc >= 0 && cc < 256) ? pp[rr * 256 + cc] : 0.f;
            }
        }
#pragma unroll
        for (int t = 0; t < 4; ++t)
#pragma unroll
            for (int dr = 0; dr < 3; ++dr)
#pragma unroll
                for (int dc = 0; dc < 3; ++dc)
                    acc[t] += win[dr][t + dc] * w9[dr * 3 + dc];
    }
    *(float4*)(out + pxb) = make_float4(acc[0], acc[1], acc[2], acc[3]);
}

// ---------------- launch ----------------
extern "C" void kernel_launch(void* const* d_in, const int* in_sizes, int n_in,
                              void* d_out, int out_size, void* d_ws, size_t ws_size,
                              hipStream_t stream) {
    (void)in_sizes; (void)n_in; (void)out_size; (void)ws_size;
    const float* x     = (const float*)d_in[0];
    const float* cw1   = (const float*)d_in[1];
    const float* cb1   = (const float*)d_in[2];
    const float* cw2   = (const float*)d_in[3];
    const float* cb2   = (const float*)d_in[4];
    const float* sw1   = (const float*)d_in[5];
    const float* sb1   = (const float*)d_in[6];
    const float* sw2   = (const float*)d_in[7];
    const float* sb2   = (const float*)d_in[8];
    const float* mkeys = (const float*)d_in[9];
    const float* mvals = (const float*)d_in[10];
    const float* mhard = (const float*)d_in[11];
    const float* dw1   = (const float*)d_in[12];
    const float* db1   = (const float*)d_in[13];
    const float* tw1   = (const float*)d_in[14];
    const float* tb1   = (const float*)d_in[15];
    const float* tw2   = (const float*)d_in[16];
    const float* tb2   = (const float*)d_in[17];
    const float* dw2   = (const float*)d_in[18];
    const float* db2   = (const float*)d_in[19];
    float* out = (float*)d_out;
    float* ws  = (float*)d_ws;

    const size_t OFF_KN  = 0;                   // knR: 800*128
    const size_t OFF_HN  = 102400;              // hn:  800*128
    const size_t OFF_C0  = 204800;              // c0 split: 2*128 shorts
    const size_t OFF_R14 = 204928;              // zc1 -> zs -> t1 granules
    const size_t OFF_R2  = OFF_R14 + 8388608;   // wse h/m/l + tconv prepped weights
    const size_t OFF_R3  = OFF_R2 + 8388608;    // zs1 -> d1 granules
    const size_t OFF_R5  = OFF_R3 + 4194304;    // dchh+dchl -> t2
    const size_t OFF_ZCQ = OFF_R5 + 16777216;   // zcq: 16*324*128
    const size_t OFF_HH  = OFF_ZCQ + 663552;    // hh
    const size_t OFF_HL  = OFF_HH + 51200;      // hl
    const size_t OFF_WH  = OFF_HL + 51200;      // wph
    const size_t OFF_WL  = OFF_WH + 73728;      // wpl
    const size_t OFF_HR  = OFF_WL + 73728;      // hardh+hardl (raw split): 102400 floats
    const size_t OFF_KNB = OFF_HR + 102400;     // knh+knl (norm key split): 102400 floats

    float* knR  = ws + OFF_KN;
    float* hn   = ws + OFF_HN;
    float* zc1  = ws + OFF_R14;
    float* zs   = ws + OFF_R14;
    float* zs1  = ws + OFF_R3;
    float* t2   = ws + OFF_R5;
    float* zcq  = ws + OFF_ZCQ;
    unsigned short* c0h  = (unsigned short*)(ws + OFF_C0);
    unsigned short* c0l  = c0h + 128;
    unsigned short* dchh = (unsigned short*)(ws + OFF_R5);   // 16*32*4096*8 shorts
    unsigned short* dchl = dchh + 16777216;
    unsigned short* hhp = (unsigned short*)(ws + OFF_HH);
    unsigned short* hlp = (unsigned short*)(ws + OFF_HL);
    unsigned short* wph = (unsigned short*)(ws + OFF_WH);
    unsigned short* wpl = (unsigned short*)(ws + OFF_WL);
    unsigned short* hardh = (unsigned short*)(ws + OFF_HR);          // 102400 shorts
    unsigned short* hardl = hardh + 102400;
    unsigned short* knh = (unsigned short*)(ws + OFF_KNB);           // 102400 shorts
    unsigned short* knl = knh + 102400;
    unsigned short* wseh = (unsigned short*)(ws + OFF_R2);           // 20480 shorts
    unsigned short* wsem = (unsigned short*)(ws + OFF_R2 + 10240);   // 20480 shorts
    unsigned short* wsel = (unsigned short*)(ws + OFF_R2 + 20480);   // 20480 shorts
    unsigned short* tw1h = (unsigned short*)(ws + OFF_R2 + 32768);   // 32768 shorts
    unsigned short* tw1l = tw1h + 32768;
    unsigned short* tw2h = tw1l + 32768;                             // 8192 shorts
    unsigned short* tw2l = tw2h + 8192;
    unsigned short* d1gh = (unsigned short*)(ws + OFF_R3);
    unsigned short* d1gl = d1gh + 4194304;
    unsigned short* t1gh = (unsigned short*)(ws + OFF_R14);
    unsigned short* t1gl = t1gh + 8388608;

    prep_norm_k<<<800, 128, 0, stream>>>(mkeys, mhard, knR, hn, hhp, hlp, hardh, hardl, knh, knl);
    prep_c0_k<<<1, 128, 0, stream>>>(mvals, c0h, c0l);
    prep_w1_k<<<576, 256, 0, stream>>>(dw1, wph, wpl);
    prep_wse_k<<<80, 256, 0, stream>>>(sw2, wseh, wsem, wsel);
    prep_tw<64, 32><<<128, 256, 0, stream>>>(tw1, tw1h, tw1l);
    prep_tw<32, 16><<<32, 256, 0, stream>>>(tw2, tw2h, tw2l);

    ce1_k<<<16 * 2 * 6, 256, 0, stream>>>(x, cw1, cb1, zc1);
    se1_k<<<16 * 64, 256, 0, stream>>>(x, sw1, sb1, zs1);
    ce2_v3<<<16 * 16, 256, 0, stream>>>(zc1, cw2, cb2, zcq);
    se2_mfma<<<16 * 64, 256, 0, stream>>>(zs1, wseh, wsem, wsel, sb2, zs);  // overwrites zc1 (dead)

    match_center_v3<<<324, 256, 0, stream>>>(zcq, knR, knh, knl, mvals, dchh, dchl);
    fill_c0_k<<<4096, 256, 0, stream>>>(c0h, c0l, dchh, dchl);
    match_skip_v8<<<16 * 64, 256, 0, stream>>>(zs, hn, hhp, hlp, hardh, hardl, dchh, dchl);

    dec1_v14<<<2048, 256, 0, stream>>>(dchh, dchl, wph, wpl, db1, d1gh, d1gl);  // overwrites zs1 (dead)

    tconv_m<64, 32, 64, false, true><<<16 * 64, 256, 0, stream>>>(
        d1gh, d1gl, tw1h, tw1l, tb1, nullptr, t1gh, t1gl);       // overwrites zs (dead)
    tconv_m<32, 16, 128, true, false><<<16 * 128, 256, 0, stream>>>(
        t1gh, t1gl, tw2h, tw2l, tb2, t2, nullptr, nullptr);      // overwrites dchh/dchl (dead)
    final_v2<<<1024, 256, 0, stream>>>(t2, dw2, db2, out);
}

// Round 15
// 552.943 us; speedup vs baseline: 1.2508x; 1.2508x over previous
//
#include <hip/hip_runtime.h>
#include <cstdint>
#include <cstddef>

#define NEG_INF (-3.0e38f)

typedef __attribute__((ext_vector_type(8))) short short8;
typedef __attribute__((ext_vector_type(4))) float f32x4;

__device__ inline unsigned short bf16_rne(float x) {
    unsigned u = __float_as_uint(x);
    unsigned r = u + 0x7fffu + ((u >> 16) & 1u);
    return (unsigned short)(r >> 16);
}
__device__ inline float bf16_tof(unsigned short h) {
    return __uint_as_float(((unsigned)h) << 16);
}

// async global->LDS 16B copy: dest must be wave-uniform base + lane*16
__device__ inline void gll16(const void* gsrc, void* ldst) {
    __builtin_amdgcn_global_load_lds(
        (const __attribute__((address_space(1))) unsigned int*)gsrc,
        (__attribute__((address_space(3))) unsigned int*)ldst, 16, 0, 0);
}

// ---------------- prep: normalize keys/hard + bf16 splits ----------------
__global__ void prep_norm_k(const float* __restrict__ keys,
                            const float* __restrict__ hard,
                            float* __restrict__ knR,   // [800][128] normalized keys
                            float* __restrict__ hn,    // [800][128] normalized hard
                            unsigned short* __restrict__ hh,  // [800][128] bf16 hi (norm hard)
                            unsigned short* __restrict__ hl,  // [800][128] bf16 lo (norm hard)
                            unsigned short* __restrict__ hardh,  // [800][128] bf16 hi (raw hard)
                            unsigned short* __restrict__ hardl,  // [800][128] bf16 lo (raw hard)
                            unsigned short* __restrict__ knh,    // [800][128] bf16 hi (norm keys)
                            unsigned short* __restrict__ knl) {  // [800][128] bf16 lo (norm keys)
    int m = blockIdx.x;      // 0..799
    int c = threadIdx.x;     // 0..127
    float kv = keys[m * 128 + c];
    float hv = hard[m * 128 + c];
    __shared__ float s1[128];
    __shared__ float s2[128];
    s1[c] = kv * kv;
    s2[c] = hv * hv;
    __syncthreads();
    for (int off = 64; off > 0; off >>= 1) {
        if (c < off) { s1[c] += s1[c + off]; s2[c] += s2[c + off]; }
        __syncthreads();
    }
    float ks = 1.0f / fmaxf(sqrtf(s1[0]), 1e-12f);
    float hs = 1.0f / fmaxf(sqrtf(s2[0]), 1e-12f);
    float knv = kv * ks;
    knR[m * 128 + c] = knv;
    unsigned short kh = bf16_rne(knv);
    knh[m * 128 + c] = kh;
    knl[m * 128 + c] = bf16_rne(knv - bf16_tof(kh));
    float hnv = hv * hs;
    hn[m * 128 + c] = hnv;
    unsigned short hi = bf16_rne(hnv);
    hh[m * 128 + c] = hi;
    hl[m * 128 + c] = bf16_rne(hnv - bf16_tof(hi));
    unsigned short rh = bf16_rne(hv);
    hardh[m * 128 + c] = rh;
    hardl[m * 128 + c] = bf16_rne(hv - bf16_tof(rh));
}

// prep_c0 emits the bf16 split directly (consumed by fill_c0 granule writes)
__global__ void prep_c0_k(const float* __restrict__ values,
                          unsigned short* __restrict__ c0h,
                          unsigned short* __restrict__ c0l) {
    int c = threadIdx.x;  // 128 threads
    float s = 0.f;
    for (int m = 0; m < 10; ++m) s += values[m * 128 + c];
    s *= 0.1f;
    unsigned short h = bf16_rne(s);
    c0h[c] = h;
    c0l[c] = bf16_rne(s - bf16_tof(h));
}

// ---------------- prep: dec1 weights -> chunked bf16 hi/lo, MFMA A-layout w/ bank swizzle ----------------
__global__ void prep_w1_k(const float* __restrict__ dw1,   // (64,256,3,3)
                          unsigned short* __restrict__ wph,
                          unsigned short* __restrict__ wpl) {
    int idx = blockIdx.x * 256 + threadIdx.x;   // 147456 total
    int co = idx / 2304, r2 = idx % 2304;
    int ci = r2 / 9, tap = r2 % 9;
    float v = dw1[idx];
    int chunk = ci >> 5, cog = co >> 5, co32 = co & 31;
    int cil = ci & 31, g = cil >> 3, j = cil & 7;
    int gs = g ^ ((co32 >> 2) & 3);
    int off = ((((chunk * 9 + tap) * 2 + cog) * 32 + co32) * 4 + gs) * 8 + j;
    unsigned short hi = bf16_rne(v);
    wph[off] = hi;
    wpl[off] = bf16_rne(v - bf16_tof(hi));
}

// ---------------- prep: se2 weights -> triple bf16 split, MFMA A-fragment layout ----------------
__global__ void prep_wse_k(const float* __restrict__ sw2,   // (128,16,3,3)
                           unsigned short* __restrict__ wh,
                           unsigned short* __restrict__ wm,
                           unsigned short* __restrict__ wl) {
    int idx = blockIdx.x * 256 + threadIdx.x;   // 20480 total
    if (idx >= 20480) return;
    int chunk = idx >> 12;
    int rem = idx & 4095;
    int co = rem >> 5;
    int quad = (rem >> 3) & 3;
    int j = rem & 7;
    int tap = chunk * 2 + (quad >> 1);
    int ci = ((quad & 1) << 3) + j;
    float v = (tap < 9) ? sw2[(co * 16 + ci) * 9 + tap] : 0.f;
    unsigned short h = bf16_rne(v);
    float r1 = v - bf16_tof(h);
    unsigned short m_ = bf16_rne(r1);
    float r2 = r1 - bf16_tof(m_);
    wh[idx] = h;
    wm[idx] = m_;
    wl[idx] = bf16_rne(r2);
}

// ---------------- prep: tconv weights -> parity-GEMM A-fragment layout, bf16 hi/lo ----------------
template <int CIN, int COUT>
__global__ void prep_tw(const float* __restrict__ tw,   // (CIN,COUT,4,4)
                        unsigned short* __restrict__ ph,
                        unsigned short* __restrict__ pl) {
    constexpr int GR = CIN / 8;
    constexpr int NKS = CIN / 8;
    int idx = blockIdx.x * 256 + threadIdx.x;
    if (idx >= CIN * COUT * 16) return;
    int j = idx & 7;
    int t1 = idx >> 3;
    int co = t1 % COUT; int t2 = t1 / COUT;
    int quad = t2 & 3; int t3 = t2 >> 2;
    int ks = t3 % NKS; int p = t3 / NKS;
    int kq = ks * 4 + quad;
    int tap = kq / GR, cig = kq % GR;
    int ci = cig * 8 + j;
    int a = tap >> 1, bb = tap & 1;
    int pr = p >> 1, pc = p & 1;
    float v = tw[(((size_t)ci * COUT + co) << 4) + (3 - pr - 2 * a) * 4 + (3 - pc - 2 * bb)];
    unsigned short h = bf16_rne(v);
    ph[idx] = h;
    pl[idx] = bf16_rne(v - bf16_tof(h));
}

// ---------------- center conv1+pool: only pooled rect [45,83)^2 ----------------
__global__ void ce1_k(const float* __restrict__ x,   // (16,1,256,256)
                      const float* __restrict__ w,   // (32,1,3,3)
                      const float* __restrict__ bias,
                      float* __restrict__ out) {     // (16,32,128,128) rect only
    int bx = blockIdx.x;            // 16 b * 2 cog * 6 tiles
    int b = bx / 12, rem = bx % 12;
    int cog = rem / 6, tile = rem % 6;
    int idx = tile * 256 + threadIdx.x;
    if (idx >= 1444) return;
    int ph = 45 + idx / 38, pw = 45 + idx % 38;
    const float* xb = x + (size_t)b * 65536;
    float win[4][4];
#pragma unroll
    for (int r = 0; r < 4; ++r) {
        int ih = 2 * ph - 1 + r;
        bool vr = (ih >= 96 && ih < 160);
#pragma unroll
        for (int c = 0; c < 4; ++c) {
            int iw = 2 * pw - 1 + c;
            win[r][c] = (vr && iw >= 96 && iw < 160) ? xb[ih * 256 + iw] : 0.f;
        }
    }
#pragma unroll
    for (int co8 = 0; co8 < 16; ++co8) {
        int co = cog * 16 + co8;
        const float* w9 = w + co * 9;
        float bv = bias[co];
        float a00 = bv, a01 = bv, a10 = bv, a11 = bv;
#pragma unroll
        for (int kh = 0; kh < 3; ++kh)
#pragma unroll
            for (int kw = 0; kw < 3; ++kw) {
                float wv = w9[kh * 3 + kw];
                a00 += win[kh][kw] * wv;
                a01 += win[kh][kw + 1] * wv;
                a10 += win[kh + 1][kw] * wv;
                a11 += win[kh + 1][kw + 1] * wv;
            }
        float mx = fmaxf(fmaxf(a00, a01), fmaxf(a10, a11));
        out[((size_t)b * 32 + co) * 16384 + ph * 128 + pw] = fmaxf(mx, 0.f);
    }
}

// ---------------- skip conv1+pool: full, 16 co per thread ----------------
__global__ void se1_k(const float* __restrict__ x,   // (16,1,256,256)
                      const float* __restrict__ w,   // (16,1,3,3)
                      const float* __restrict__ bias,
                      float* __restrict__ out) {     // (16,16,128,128)
    int bx = blockIdx.x;            // 16 b * 64 tiles
    int b = bx >> 6, tile = bx & 63;
    int idx = tile * 256 + threadIdx.x;   // 0..16383
    int ph = idx >> 7, pw = idx & 127;
    const float* xb = x + (size_t)b * 65536;
    float win[4][4];
#pragma unroll
    for (int r = 0; r < 4; ++r) {
        int ih = 2 * ph - 1 + r;
        bool vr = (ih >= 0 && ih < 256);
#pragma unroll
        for (int c = 0; c < 4; ++c) {
            int iw = 2 * pw - 1 + c;
            win[r][c] = (vr && iw >= 0 && iw < 256) ? xb[ih * 256 + iw] : 0.f;
        }
    }
#pragma unroll
    for (int co = 0; co < 16; ++co) {
        const float* w9 = w + co * 9;
        float bv = bias[co];
        float a00 = bv, a01 = bv, a10 = bv, a11 = bv;
#pragma unroll
        for (int kh = 0; kh < 3; ++kh)
#pragma unroll
            for (int kw = 0; kw < 3; ++kw) {
                float wv = w9[kh * 3 + kw];
                a00 += win[kh][kw] * wv;
                a01 += win[kh][kw + 1] * wv;
                a10 += win[kh + 1][kw] * wv;
                a11 += win[kh + 1][kw + 1] * wv;
            }
        float mx = fmaxf(fmaxf(a00, a01), fmaxf(a10, a11));
        out[((size_t)b * 16 + co) * 16384 + idx] = fmaxf(mx, 0.f);
    }
}

// ---------------- center conv2 v3 (32->128) + relu + pool -> query-major zcq ----------------
__global__ void __launch_bounds__(256) ce2_v3(
        const float* __restrict__ zc1,  // (16,32,128,128)
        const float* __restrict__ w,    // (128,32,3,3)
        const float* __restrict__ bias,
        float* __restrict__ zcq) {      // (16*324, 128) query-major
    int bx = blockIdx.x;                // 16 b * 16 cog
    int b = bx >> 4, cog = bx & 15;
    const float* ib = zc1 + (size_t)b * 32 * 16384;
    for (int px = threadIdx.x; px < 324; px += 256) {
        int h = 23 + px / 18, ww = 23 + px % 18;
        float acc[8][4];
#pragma unroll
        for (int c8 = 0; c8 < 8; ++c8)
#pragma unroll
            for (int t = 0; t < 4; ++t) acc[c8][t] = 0.f;
        for (int ci = 0; ci < 32; ++ci) {
            const float* p = ib + ci * 16384 + (2 * h - 1) * 128 + (2 * ww - 1);
            float win[4][4];
#pragma unroll
            for (int r = 0; r < 4; ++r)
#pragma unroll
                for (int s = 0; s < 4; ++s) win[r][s] = p[r * 128 + s];
#pragma unroll
            for (int c8 = 0; c8 < 8; ++c8) {
                const float* w9 = w + ((size_t)(cog * 8 + c8) * 32 + ci) * 9;
#pragma unroll
                for (int kh = 0; kh < 3; ++kh)
#pragma unroll
                    for (int kw = 0; kw < 3; ++kw) {
                        float wv = w9[kh * 3 + kw];
                        acc[c8][0] += win[kh][kw] * wv;
                        acc[c8][1] += win[kh][kw + 1] * wv;
                        acc[c8][2] += win[kh + 1][kw] * wv;
                        acc[c8][3] += win[kh + 1][kw + 1] * wv;
                    }
            }
        }
#pragma unroll
        for (int c8 = 0; c8 < 8; ++c8) {
            int co = cog * 8 + c8;
            float mx = fmaxf(fmaxf(acc[c8][0], acc[c8][1]), fmaxf(acc[c8][2], acc[c8][3])) + bias[co];
            zcq[((size_t)(b * 324 + px)) * 128 + co] = fmaxf(mx, 0.f);
        }
    }
}

// ---------------- skip conv2 (16->128) + relu + pool via MFMA, triple bf16 split ----------------
__global__ void __launch_bounds__(256, 2) se2_mfma(
        const float* __restrict__ zs1,   // (16,16,128,128)
        const unsigned short* __restrict__ wh,
        const unsigned short* __restrict__ wm,
        const unsigned short* __restrict__ wl,
        const float* __restrict__ bias,
        float* __restrict__ zs) {        // (16,128,64,64)
    __shared__ unsigned short sm[24960];   // 3 x 8320 shorts (h, m, l)
    int b = blockIdx.x >> 6, pr = blockIdx.x & 63;
    int tid = threadIdx.x;
    int w = tid >> 6, lane = tid & 63;
    int l15 = lane & 15, quad = lane >> 4;

    for (int f = tid; f < 4160; f += 256) {
        int ci2 = f / 520;                 // 0..7 (ci pair index)
        int rem = f - ci2 * 520;
        int wr = rem / 130;
        int col = rem - wr * 130;
        int gr = 2 * pr - 1 + wr;
        int gc = col - 1;
        float v0 = 0.f, v1 = 0.f;
        if (gr >= 0 && gr < 128 && gc >= 0 && gc < 128) {
            const float* p = zs1 + ((size_t)(b * 16 + ci2 * 2) * 128 + gr) * 128 + gc;
            v0 = p[0];
            v1 = p[16384];
        }
        unsigned short h0 = bf16_rne(v0);
        float r0 = v0 - bf16_tof(h0);
        unsigned short m0 = bf16_rne(r0);
        unsigned short l0 = bf16_rne(r0 - bf16_tof(m0));
        unsigned short h1 = bf16_rne(v1);
        float r1 = v1 - bf16_tof(h1);
        unsigned short m1 = bf16_rne(r1);
        unsigned short l1 = bf16_rne(r1 - bf16_tof(m1));
        int off = (((ci2 >> 2) * 4 + wr) * 130 + col) * 8 + ((ci2 & 3) << 1);
        *(unsigned*)&sm[off]         = (unsigned)h0 | ((unsigned)h1 << 16);
        *(unsigned*)&sm[8320 + off]  = (unsigned)m0 | ((unsigned)m1 << 16);
        *(unsigned*)&sm[16640 + off] = (unsigned)l0 | ((unsigned)l1 << 16);
    }
    __syncthreads();

    const unsigned short* xh = sm;
    const unsigned short* xm = sm + 8320;
    const unsigned short* xl = sm + 16640;

    int ct0 = w * 16, ct1 = (w + 4) * 16;   // co bases of this wave's two tiles
    float4 bv0 = *(const float4*)(bias + ct0 + quad * 4);
    float4 bv1 = *(const float4*)(bias + ct1 + quad * 4);

    int th = quad >> 1;
    int cib = quad & 1;

    for (int q = 0; q < 8; ++q) {
        f32x4 acc[2][2];   // [co-tile][conv row]
        acc[0][0] = (f32x4){0.f, 0.f, 0.f, 0.f};
        acc[0][1] = (f32x4){0.f, 0.f, 0.f, 0.f};
        acc[1][0] = (f32x4){0.f, 0.f, 0.f, 0.f};
        acc[1][1] = (f32x4){0.f, 0.f, 0.f, 0.f};
        for (int c = 0; c < 5; ++c) {
            size_t a0 = ((size_t)(c * 128 + ct0 + l15) * 4 + quad) * 8;
            size_t a1 = ((size_t)(c * 128 + ct1 + l15) * 4 + quad) * 8;
            short8 ah0 = *(const short8*)(wh + a0);
            short8 am0 = *(const short8*)(wm + a0);
            short8 al0 = *(const short8*)(wl + a0);
            short8 ah1 = *(const short8*)(wh + a1);
            short8 am1 = *(const short8*)(wm + a1);
            short8 al1 = *(const short8*)(wl + a1);
            int tap = c * 2 + th;
            if (tap > 8) tap = 8;
            int kh = (tap >= 6) ? 2 : ((tap >= 3) ? 1 : 0);
            int kw = tap - kh * 3;
            int bcol = q * 16 + l15 + kw;
#pragma unroll
            for (int rt = 0; rt < 2; ++rt) {
                int boff = ((cib * 4 + rt + kh) * 130 + bcol) * 8;
                short8 bh = *(const short8*)(xh + boff);
                short8 bm = *(const short8*)(xm + boff);
                short8 bl = *(const short8*)(xl + boff);
                {
                    f32x4 a = acc[0][rt];
                    a = __builtin_amdgcn_mfma_f32_16x16x32_bf16(am0, bm, a, 0, 0, 0);
                    a = __builtin_amdgcn_mfma_f32_16x16x32_bf16(al0, bh, a, 0, 0, 0);
                    a = __builtin_amdgcn_mfma_f32_16x16x32_bf16(ah0, bl, a, 0, 0, 0);
                    a = __builtin_amdgcn_mfma_f32_16x16x32_bf16(am0, bh, a, 0, 0, 0);
                    a = __builtin_amdgcn_mfma_f32_16x16x32_bf16(ah0, bm, a, 0, 0, 0);
                    a = __builtin_amdgcn_mfma_f32_16x16x32_bf16(ah0, bh, a, 0, 0, 0);
                    acc[0][rt] = a;
                }
                {
                    f32x4 a = acc[1][rt];
                    a = __builtin_amdgcn_mfma_f32_16x16x32_bf16(am1, bm, a, 0, 0, 0);
                    a = __builtin_amdgcn_mfma_f32_16x16x32_bf16(al1, bh, a, 0, 0, 0);
                    a = __builtin_amdgcn_mfma_f32_16x16x32_bf16(ah1, bl, a, 0, 0, 0);
                    a = __builtin_amdgcn_mfma_f32_16x16x32_bf16(am1, bh, a, 0, 0, 0);
                    a = __builtin_amdgcn_mfma_f32_16x16x32_bf16(ah1, bm, a, 0, 0, 0);
                    a = __builtin_amdgcn_mfma_f32_16x16x32_bf16(ah1, bh, a, 0, 0, 0);
                    acc[1][rt] = a;
                }
            }
        }
        int pc = q * 8 + (l15 >> 1);
#pragma unroll
        for (int t = 0; t < 2; ++t) {
            int cbase = (t ? ct1 : ct0) + quad * 4;
            float4 bv = t ? bv1 : bv0;
#pragma unroll
            for (int u = 0; u < 4; ++u) {
                float pm = fmaxf(acc[t][0][u], acc[t][1][u]);
                pm = fmaxf(pm, __shfl_xor(pm, 1));
                if ((lane & 1) == 0) {
                    float bb = (u == 0) ? bv.x : (u == 1) ? bv.y : (u == 2) ? bv.z : bv.w;
                    zs[((size_t)(b * 128 + cbase + u)) * 4096 + pr * 64 + pc] = fmaxf(pm + bb, 0.f);
                }
            }
        }
    }
}

// ---------------- center matching v3: MFMA sims (keys direct from L2), LDS scoreboard ----------------
__global__ void __launch_bounds__(256, 2) match_center_v3(
        const float* __restrict__ zcq,    // (16*324, 128) raw queries
        const float* __restrict__ knR,    // (800,128) normalized keys fp32 (rescue)
        const unsigned short* __restrict__ knh,  // (800,128) bf16 hi
        const unsigned short* __restrict__ knl,  // (800,128) bf16 lo
        const float* __restrict__ values, // (800,128)
        unsigned short* __restrict__ dchh, // [16][32][4096][8] ch 0..127 -> G 0..15
        unsigned short* __restrict__ dchl) {
    __shared__ __align__(16) float scores[16 * 804];   // 51456 B
    __shared__ __align__(16) float qint[16 * 132];     // 8448 B
    int tid = threadIdx.x;
    int w = tid >> 6, lane = tid & 63;
    int l15 = lane & 15, quad = lane >> 4;
    int qbase = blockIdx.x * 16;

    const float* qp = zcq + (size_t)(qbase + l15) * 128;
    float qv[4][8];
    float ss = 0.f;
#pragma unroll
    for (int ks = 0; ks < 4; ++ks) {
        int c0 = (ks * 4 + quad) * 8;
        float4 a = *(const float4*)(qp + c0);
        float4 bq = *(const float4*)(qp + c0 + 4);
        qv[ks][0] = a.x; qv[ks][1] = a.y; qv[ks][2] = a.z; qv[ks][3] = a.w;
        qv[ks][4] = bq.x; qv[ks][5] = bq.y; qv[ks][6] = bq.z; qv[ks][7] = bq.w;
#pragma unroll
        for (int j = 0; j < 8; ++j) ss += qv[ks][j] * qv[ks][j];
    }
    ss += __shfl_xor(ss, 16);
    ss += __shfl_xor(ss, 32);
    float sc = 1.0f / fmaxf(sqrtf(ss), 1e-12f);
    short8 ahi[4], alo[4];
#pragma unroll
    for (int ks = 0; ks < 4; ++ks) {
#pragma unroll
        for (int j = 0; j < 8; ++j) {
            float v = qv[ks][j] * sc;
            qv[ks][j] = v;
            unsigned short h = bf16_rne(v);
            ahi[ks][j] = (short)h;
            alo[ks][j] = (short)bf16_rne(v - bf16_tof(h));
        }
    }
    if (w == 0) {
#pragma unroll
        for (int ks = 0; ks < 4; ++ks) {
            int c0 = (ks * 4 + quad) * 8;
            *(float4*)(qint + l15 * 132 + c0) =
                make_float4(qv[ks][0], qv[ks][1], qv[ks][2], qv[ks][3]);
            *(float4*)(qint + l15 * 132 + c0 + 4) =
                make_float4(qv[ks][4], qv[ks][5], qv[ks][6], qv[ks][7]);
        }
    }

    for (int kt = w; kt < 50; kt += 4) {
        f32x4 acc = (f32x4){0.f, 0.f, 0.f, 0.f};
#pragma unroll
        for (int ks = 0; ks < 4; ++ks) {
            size_t koff = ((size_t)(kt * 16 + l15) * 128) + (size_t)((ks * 4 + quad) * 8);
            short8 bhi = *(const short8*)(knh + koff);
            short8 blo = *(const short8*)(knl + koff);
            acc = __builtin_amdgcn_mfma_f32_16x16x32_bf16(alo[ks], bhi, acc, 0, 0, 0);
            acc = __builtin_amdgcn_mfma_f32_16x16x32_bf16(ahi[ks], blo, acc, 0, 0, 0);
            acc = __builtin_amdgcn_mfma_f32_16x16x32_bf16(ahi[ks], bhi, acc, 0, 0, 0);
        }
#pragma unroll
        for (int u = 0; u < 4; ++u)
            scores[(quad * 4 + u) * 804 + kt * 16 + l15] = acc[u];
    }
    __syncthreads();

    for (int qi = 0; qi < 4; ++qi) {
        int q = w * 4 + qi;
        int g = qbase + q;
        int b = g / 324, qq = g - b * 324;
        int h = 23 + qq / 18, ww2 = 23 + qq % 18;
        int p = h * 64 + ww2;

        float sim[13];
#pragma unroll
        for (int k = 0; k < 13; ++k)
            sim[k] = (lane + (k << 6) < 800) ? scores[q * 804 + lane + (k << 6)] : NEG_INF;

        float topv[11]; int topm[11];
#pragma unroll
        for (int t = 0; t < 11; ++t) {
            float bvv = NEG_INF; int bm = 0x7fffffff;
#pragma unroll
            for (int k = 0; k < 13; ++k) {
                if (sim[k] > bvv) { bvv = sim[k]; bm = lane + (k << 6); }
            }
#pragma unroll
            for (int off = 32; off > 0; off >>= 1) {
                float ov = __shfl_xor(bvv, off);
                int om = __shfl_xor(bm, off);
                if (ov > bvv || (ov == bvv && om < bm)) { bvv = ov; bm = om; }
            }
            topv[t] = bvv; topm[t] = bm;
            if ((bm & 63) == lane) {
                int kk = bm >> 6;
#pragma unroll
                for (int k = 0; k < 13; ++k)
                    if (k == kk) sim[k] = NEG_INF;
            }
        }
        if (topv[9] - topv[10] < 1e-4f) {
            double s9 = 0.0, s10 = 0.0;
            const float* k9 = knR + (size_t)topm[9] * 128;
            const float* k10 = knR + (size_t)topm[10] * 128;
            for (int c = 0; c < 128; ++c) {
                double qc = (double)qint[q * 132 + c];
                s9 += qc * (double)k9[c];
                s10 += qc * (double)k10[c];
            }
            if ((s10 > s9) || (s10 == s9 && topm[10] < topm[9])) {
                topv[9] = topv[10]; topm[9] = topm[10];
            }
        }
        float mx = topv[0];
        float e[10], ssum = 0.f;
#pragma unroll
        for (int t = 0; t < 10; ++t) { e[t] = expf(topv[t] - mx); ssum += e[t]; }
        float inv = 1.0f / ssum;
        float o0 = 0.f, o1 = 0.f;
#pragma unroll
        for (int t = 0; t < 10; ++t) {
            float wt = e[t] * inv;
            const float* vr = values + (size_t)topm[t] * 128;
            o0 += wt * vr[lane];
            o1 += wt * vr[lane + 64];
        }
        unsigned short h0 = bf16_rne(o0);
        unsigned short l0 = bf16_rne(o0 - bf16_tof(h0));
        unsigned short h1 = bf16_rne(o1);
        unsigned short l1 = bf16_rne(o1 - bf16_tof(h1));
        size_t a0 = ((size_t)(b * 32 + (lane >> 3)) * 4096 + p) * 8 + (lane & 7);
        size_t a1 = ((size_t)(b * 32 + 8 + (lane >> 3)) * 4096 + p) * 8 + (lane & 7);
        dchh[a0] = h0; dchl[a0] = l0;
        dchh[a1] = h1; dchl[a1] = l1;
    }
}

// ---------------- constant fill for out-of-region center matches (granule writes) ----------------
__global__ void fill_c0_k(const unsigned short* __restrict__ c0h,
                          const unsigned short* __restrict__ c0l,
                          unsigned short* __restrict__ dchh,
                          unsigned short* __restrict__ dchl) {
    int idx = blockIdx.x * 256 + threadIdx.x;  // 16b * 16G * 4096p = 1048576
    int p = idx & 4095;
    int G = (idx >> 12) & 15;
    int b = idx >> 16;
    int h = p >> 6, ww = p & 63;
    if (h >= 23 && h <= 40 && ww >= 23 && ww <= 40) return;
    uint4 vh = *(const uint4*)(c0h + G * 8);
    uint4 vl = *(const uint4*)(c0l + G * 8);
    size_t off = ((size_t)(b * 32 + G) * 4096 + p) * 8;
    *(uint4*)(dchh + off) = vh;
    *(uint4*)(dchl + off) = vl;
}

// ---------------- skip matching v7: reg queries, dbuf gll16 keys, branch-free top-2 ----------------
__global__ void __launch_bounds__(256, 4) match_skip_v7(
        const float* __restrict__ zs,    // (16,128,64,64) raw queries
        const float* __restrict__ hn,    // (800,128) normalized fp32 (rescore)
        const unsigned short* __restrict__ hh,  // (800,128) bf16 hi
        const unsigned short* __restrict__ hl,  // (800,128) bf16 lo
        const unsigned short* __restrict__ hardh,  // (800,128) raw bf16 hi
        const unsigned short* __restrict__ hardl,  // (800,128) raw bf16 lo
        unsigned short* __restrict__ dchh,  // G 16..31 (ch 128..255)
        unsigned short* __restrict__ dchl) {
    __shared__ __align__(16) unsigned short sm[16640];
    int b = blockIdx.x >> 6, pt = blockIdx.x & 63;
    int pbase = pt * 64;
    int tid = threadIdx.x;
    int w = tid >> 6, lane = tid & 63;
    int l15 = lane & 15, quad = lane >> 4;

    int s0 = tid, s1 = tid + 256;
    int g0 = (s0 >> 4) * 128 + (((s0 & 15) ^ ((s0 >> 4) & 15)) << 3);
    int g1 = (s1 >> 4) * 128 + (((s1 & 15) ^ ((s1 >> 4) & 15)) << 3);
    int d0 = s0 * 8, d1 = s1 * 8;

    gll16(hh + g0, &sm[d0]);
    gll16(hh + g1, &sm[d1]);
    gll16(hl + g0, &sm[4096 + d0]);
    gll16(hl + g1, &sm[4096 + d1]);

    int qrow = 16 * w + l15;
    const float* zq = zs + ((size_t)b * 128) * 4096 + pbase + qrow;
    short8 ahi[4], alo[4];
    float qn2p = 0.f;
#pragma unroll
    for (int ks = 0; ks < 4; ++ks) {
        int cb = ks * 4 + quad;
#pragma unroll
        for (int j = 0; j < 8; ++j) {
            float v = zq[(size_t)(cb * 8 + j) * 4096];
            unsigned short h = bf16_rne(v);
            ahi[ks][j] = (short)h;
            alo[ks][j] = (short)bf16_rne(v - bf16_tof(h));
            qn2p += v * v;
        }
    }
    qn2p += __shfl_xor(qn2p, 16);
    qn2p += __shfl_xor(qn2p, 32);
    float* qn2s = (float*)&sm[16384];
    if (quad == 0) qn2s[16 * w + l15] = qn2p;

    int cof[4];
#pragma unroll
    for (int ks = 0; ks < 4; ++ks)
        cof[ks] = l15 * 128 + ((((ks * 4 + quad) ^ l15)) << 3);

    float v1[4], v2[4]; int i1[4], i2[4];
#pragma unroll
    for (int u = 0; u < 4; ++u) { v1[u] = NEG_INF; v2[u] = NEG_INF; i1[u] = 0x7fffffff; i2[u] = 0x7fffffff; }

    __syncthreads();

    for (int c = 0; c < 25; ++c) {
        int bb = (c & 1) << 13;
        if (c < 24) {
            int nb = ((c + 1) & 1) << 13;
            const unsigned short* hsrc = hh + (size_t)(c + 1) * 4096;
            const unsigned short* lsrc = hl + (size_t)(c + 1) * 4096;
            gll16(hsrc + g0, &sm[nb + d0]);
            gll16(hsrc + g1, &sm[nb + d1]);
            gll16(lsrc + g0, &sm[nb + 4096 + d0]);
            gll16(lsrc + g1, &sm[nb + 4096 + d1]);
        }
        f32x4 acc[2];
        acc[0] = (f32x4){0.f, 0.f, 0.f, 0.f};
        acc[1] = (f32x4){0.f, 0.f, 0.f, 0.f};
#pragma unroll
        for (int ks = 0; ks < 4; ++ks) {
#pragma unroll
            for (int kt = 0; kt < 2; ++kt) {
                int koff = bb + kt * 2048 + cof[ks];
                short8 bhi = *(const short8*)&sm[koff];
                short8 blo = *(const short8*)&sm[koff + 4096];
                acc[kt] = __builtin_amdgcn_mfma_f32_16x16x32_bf16(alo[ks], bhi, acc[kt], 0, 0, 0);
                acc[kt] = __builtin_amdgcn_mfma_f32_16x16x32_bf16(ahi[ks], blo, acc[kt], 0, 0, 0);
                acc[kt] = __builtin_amdgcn_mfma_f32_16x16x32_bf16(ahi[ks], bhi, acc[kt], 0, 0, 0);
            }
        }
        int mb = c * 32;
#pragma unroll
        for (int kt = 0; kt < 2; ++kt) {
            int m = mb + 16 * kt + l15;
#pragma unroll
            for (int u = 0; u < 4; ++u) {
                float sv = acc[kt][u];
                bool b1 = sv > v1[u];
                bool b2 = sv > v2[u];
                float nv2 = b1 ? v1[u] : (b2 ? sv : v2[u]);
                int   ni2 = b1 ? i1[u] : (b2 ? m : i2[u]);
                v1[u] = b1 ? sv : v1[u];
                i1[u] = b1 ? m : i1[u];
                v2[u] = nv2; i2[u] = ni2;
            }
        }
        __syncthreads();
    }

    float4* red = (float4*)&sm[0];
#pragma unroll
    for (int u = 0; u < 4; ++u) {
        int q = 16 * w + quad * 4 + u;
        red[q * 17 + l15] = make_float4(v1[u], v2[u], __int_as_float(i1[u]), __int_as_float(i2[u]));
    }
    __syncthreads();
    int* bi_sh = (int*)&sm[16512];
    if (tid < 64) {
        int q = tid;
        float V1 = NEG_INF; int I1 = 0x7fffffff;
        for (int k = 0; k < 16; ++k) {
            float4 e = red[q * 17 + k];
            float cv[2] = { e.x, e.y };
            int ci_[2] = { __float_as_int(e.z), __float_as_int(e.w) };
#pragma unroll
            for (int t = 0; t < 2; ++t) {
                if (cv[t] > V1 || (cv[t] == V1 && ci_[t] < I1)) { V1 = cv[t]; I1 = ci_[t]; }
            }
        }
        float tau = 1.5e-4f * sqrtf(qn2s[q]) + 1e-12f;
        float thr = V1 - tau;
        int ncand = 0;
        for (int k = 0; k < 16; ++k) {
            float4 e = red[q * 17 + k];
            if (e.x >= thr && __float_as_int(e.z) != 0x7fffffff) ++ncand;
            if (e.y >= thr && __float_as_int(e.w) != 0x7fffffff) ++ncand;
        }
        int bi = I1;
        if (ncand > 1) {
            double bestd = -1.0e300; int besti = 0x7fffffff;
            for (int k = 0; k < 16; ++k) {
                float4 e = red[q * 17 + k];
                float cv[2] = { e.x, e.y };
                int ci_[2] = { __float_as_int(e.z), __float_as_int(e.w) };
                for (int t = 0; t < 2; ++t) {
                    if (cv[t] >= thr && ci_[t] != 0x7fffffff) {
                        const float* hr = hn + (size_t)ci_[t] * 128;
                        double d = 0.0;
                        for (int c = 0; c < 128; ++c) {
                            double qc = (double)zs[((size_t)b * 128 + c) * 4096 + pbase + q];
                            d += qc * (double)hr[c];
                        }
                        if (d > bestd || (d == bestd && ci_[t] < besti)) { bestd = d; besti = ci_[t]; }
                    }
                }
            }
            bi = besti;
        }
        bi_sh[q] = bi;
    }
    __syncthreads();
    {
        int q = tid & 63, seg = tid >> 6;
        int bi = bi_sh[q];
        const unsigned short* hhr = hardh + (size_t)bi * 128;
        const unsigned short* hlr = hardl + (size_t)bi * 128;
        size_t pb = (size_t)pbase + q;
#pragma unroll
        for (int gi = 0; gi < 4; ++gi) {
            int cb = seg * 32 + gi * 8;          // 0..127 within skip half
            int G = 16 + (cb >> 3);              // global granule 16..31
            uint4 vh = *(const uint4*)(hhr + cb);
            uint4 vl = *(const uint4*)(hlr + cb);
            size_t off = ((size_t)(b * 32 + G) * 4096 + pb) * 8;
            *(uint4*)(dchh + off) = vh;
            *(uint4*)(dchl + off) = vl;
        }
    }
}

// ---------------- decoder conv1 v14: v11 structure + XCD-pairing block swizzle ----------------
__global__ void __launch_bounds__(256, 2) dec1_v14(
        const unsigned short* __restrict__ dch,  // hi granules [16][32][4096][8]
        const unsigned short* __restrict__ dcl,  // lo granules
        const unsigned short* __restrict__ wph,  // prepped weights hi
        const unsigned short* __restrict__ wpl,  // prepped weights lo
        const float* __restrict__ bias,
        unsigned short* __restrict__ d1gh,  // out granules [16][8][4096][8]
        unsigned short* __restrict__ d1gl) {
    __shared__ unsigned short smem[31104];  // x: hi [0,6336), lo [6336,12672); w: [12672,31104)
    int bxh = blockIdx.x;               // hardware index 0..2047
    int grp = bxh >> 4, rem16 = bxh & 15;
    int cog = rem16 >> 3, sub = rem16 & 7;
    int li = grp * 8 + sub;             // logical (b,r0) 0..1023
    int b = li >> 6, r0 = li & 63;
    int tid = threadIdx.x;
    int w = tid >> 6, lane = tid & 63;
    int l15 = lane & 15, quad = lane >> 4;
    int mt = w & 1, nh = w >> 1;
    int gx = quad ^ ((l15 >> 2) & 3);

    {
        uint4 z = make_uint4(0u, 0u, 0u, 0u);
        for (int f = tid; f < 1584; f += 256)
            *(uint4*)&smem[f * 8] = z;
    }

    bool vld[3];
    int gof[3], lof[3];
#pragma unroll
    for (int k = 0; k < 3; ++k) {
        int gr = r0 - 1 + k;
        vld[k] = (gr >= 0 && gr < 64);          // block-uniform
        gof[k] = ((b * 32 + w) * 4096 + gr * 64 + lane) * 8;
        lof[k] = ((k * 4 + w) * 66 + lane + 1) * 8;
    }
    __syncthreads();

#pragma unroll
    for (int k = 0; k < 3; ++k)
        if (vld[k]) {
            gll16(dch + gof[k], &smem[lof[k]]);
            gll16(dcl + gof[k], &smem[6336 + lof[k]]);
        }
#pragma unroll
    for (int k = 0; k < 5; ++k) {
        int t = tid + k * 256;
        if (t < 1152) {
            int tap = t >> 7, wi = t & 127;
            size_t src = ((size_t)((0 * 9 + tap) * 2 + cog)) * 1024 + wi * 8;
            int dst = 12672 + tap * 1024 + wi * 8;
            gll16(wph + src, &smem[dst]);
            gll16(wpl + src, &smem[dst + 9216]);
        }
    }
    __syncthreads();

    f32x4 acc[2];
    acc[0] = (f32x4){0.f, 0.f, 0.f, 0.f};
    acc[1] = (f32x4){0.f, 0.f, 0.f, 0.f};

    for (int chunk = 0; chunk < 8; ++chunk) {
#pragma unroll
        for (int tap = 0; tap < 9; ++tap) {
            int kh = tap / 3, kw = tap % 3;
            int aoff = 12672 + tap * 1024 + (mt * 16 + l15) * 32 + gx * 8;
            short8 ahi = *(const short8*)&smem[aoff];
            short8 alo = *(const short8*)&smem[aoff + 9216];
#pragma unroll
            for (int n2 = 0; n2 < 2; ++n2) {
                int nt = nh * 2 + n2;
                int boff = ((kh * 4 + quad) * 66 + nt * 16 + l15 + kw) * 8;
                short8 bhi = *(const short8*)&smem[boff];
                short8 blo = *(const short8*)&smem[boff + 6336];
                acc[n2] = __builtin_amdgcn_mfma_f32_16x16x32_bf16(alo, bhi, acc[n2], 0, 0, 0);
                acc[n2] = __builtin_amdgcn_mfma_f32_16x16x32_bf16(ahi, blo, acc[n2], 0, 0, 0);
                acc[n2] = __builtin_amdgcn_mfma_f32_16x16x32_bf16(ahi, bhi, acc[n2], 0, 0, 0);
            }
        }
        if (chunk < 7) {
            __syncthreads();
            int coff = (chunk + 1) * 131072;
#pragma unroll
            for (int k = 0; k < 3; ++k)
                if (vld[k]) {
                    gll16(dch + gof[k] + coff, &smem[lof[k]]);
                    gll16(dcl + gof[k] + coff, &smem[6336 + lof[k]]);
                }
#pragma unroll
            for (int k = 0; k < 5; ++k) {
                int t = tid + k * 256;
                if (t < 1152) {
                    int tap = t >> 7, wi = t & 127;
                    size_t src = ((size_t)(((chunk + 1) * 9 + tap) * 2 + cog)) * 1024 + wi * 8;
                    int dst = 12672 + tap * 1024 + wi * 8;
                    gll16(wph + src, &smem[dst]);
                    gll16(wpl + src, &smem[dst + 9216]);
                }
            }
            __syncthreads();
        }
    }
    int co0 = cog * 32 + mt * 16 + quad * 4;
    int G = co0 >> 3, j0 = co0 & 7;
    float4 bv = *(const float4*)(bias + co0);
#pragma unroll
    for (int n2 = 0; n2 < 2; ++n2) {
        int nt = nh * 2 + n2;
        int px = r0 * 64 + nt * 16 + l15;
        float v0 = fmaxf(acc[n2][0] + bv.x, 0.f);
        float v1 = fmaxf(acc[n2][1] + bv.y, 0.f);
        float v2 = fmaxf(acc[n2][2] + bv.z, 0.f);
        float v3 = fmaxf(acc[n2][3] + bv.w, 0.f);
        unsigned short h0 = bf16_rne(v0), h1 = bf16_rne(v1), h2 = bf16_rne(v2), h3 = bf16_rne(v3);
        unsigned short l0 = bf16_rne(v0 - bf16_tof(h0)), l1 = bf16_rne(v1 - bf16_tof(h1));
        unsigned short l2 = bf16_rne(v2 - bf16_tof(h2)), l3 = bf16_rne(v3 - bf16_tof(h3));
        size_t off = ((size_t)(b * 8 + G) * 4096 + px) * 8 + j0;
        *(uint2*)(d1gh + off) = make_uint2((unsigned)h0 | ((unsigned)h1 << 16),
                                           (unsigned)h2 | ((unsigned)h3 << 16));
        *(uint2*)(d1gl + off) = make_uint2((unsigned)l0 | ((unsigned)l1 << 16),
                                           (unsigned)l2 | ((unsigned)l3 << 16));
    }
}

// ---------------- transposed conv via MFMA: 4 parity GEMMs, granule input, gll16 staging ----------
template <int CIN, int COUT, int H, bool WIDE, bool GRANOUT>
__global__ void __launch_bounds__(256) tconv_m(
        const unsigned short* __restrict__ xgh,  // [16][CIN/8][H][H][8]
        const unsigned short* __restrict__ xgl,
        const unsigned short* __restrict__ wth,  // [4][NKS][4][COUT][8]
        const unsigned short* __restrict__ wtl,
        const float* __restrict__ bias,
        float* __restrict__ outf,                // (16,COUT,2H,2H) if !GRANOUT
        unsigned short* __restrict__ goh,        // [16][COUT/8][2H][2H][8] if GRANOUT
        unsigned short* __restrict__ gol) {
    constexpr int GR = CIN / 8;
    constexpr int NKS = CIN / 8;
    constexpr int COLS = H + 2;
    constexpr int XSZ = 3 * GR * COLS * 8;
    __shared__ __align__(16) unsigned short sm[2 * XSZ];
    int b = blockIdx.x / H, i = blockIdx.x % H;
    int tid = threadIdx.x, w = tid >> 6, lane = tid & 63;
    int l15 = lane & 15, quad = lane >> 4;

    {
        uint4 z = make_uint4(0u, 0u, 0u, 0u);
        for (int f = tid; f < (2 * XSZ) / 8; f += 256) *(uint4*)&sm[f * 8] = z;
    }
    __syncthreads();
    for (int t = w; t < 3 * GR * (WIDE ? 2 : 1); t += 4) {
        int r, g, ch;
        if (WIDE) { r = t >> 3; int s = t & 7; g = s >> 1; ch = s & 1; }
        else      { r = t / GR; g = t % GR; ch = 0; }
        int rg = i - 1 + r;
        if (rg >= 0 && rg < H) {   // wave-uniform
            int col = ch * 64 + lane;
            int dst = ((r * GR + g) * COLS + col + 1) * 8;
            size_t src = ((size_t)((b * GR + g) * H + rg) * H + col) * 8;
            gll16(xgh + src, &sm[dst]);
            gll16(xgl + src, &sm[XSZ + dst]);
        }
    }
    __syncthreads();

    int pr = w >> 1;
    int wh2 = WIDE ? (w & 1) : 0;
    int mt = WIDE ? 0 : (w & 1);
    int co0 = mt * 16 + quad * 4;
    float4 bv = *(const float4*)(bias + co0);

    for (int pc = 0; pc < 2; ++pc) {
        int p = pr * 2 + pc;
        f32x4 acc[4];
#pragma unroll
        for (int nt = 0; nt < 4; ++nt) acc[nt] = (f32x4){0.f, 0.f, 0.f, 0.f};
#pragma unroll
        for (int ks = 0; ks < NKS; ++ks) {
            size_t aoff = ((size_t)(((p * NKS + ks) * 4 + quad) * COUT) + mt * 16 + l15) * 8;
            short8 ahi = *(const short8*)(wth + aoff);
            short8 alo = *(const short8*)(wtl + aoff);
            int kq = ks * 4 + quad;
            int tap = kq / GR, cig = kq % GR;
            int irow = pr + (tap >> 1);
            int cadd = pc + (tap & 1);
#pragma unroll
            for (int nt = 0; nt < 4; ++nt) {
                int jcol = (wh2 * 4 + nt) * 16 + l15;
                int boff = ((irow * GR + cig) * COLS + jcol + cadd) * 8;
                short8 bhi = *(const short8*)&sm[boff];
                short8 blo = *(const short8*)&sm[XSZ + boff];
                acc[nt] = __builtin_amdgcn_mfma_f32_16x16x32_bf16(alo, bhi, acc[nt], 0, 0, 0);
                acc[nt] = __builtin_amdgcn_mfma_f32_16x16x32_bf16(ahi, blo, acc[nt], 0, 0, 0);
                acc[nt] = __builtin_amdgcn_mfma_f32_16x16x32_bf16(ahi, bhi, acc[nt], 0, 0, 0);
            }
        }
#pragma unroll
        for (int nt = 0; nt < 4; ++nt) {
            int jcol = (wh2 * 4 + nt) * 16 + l15;
            int orow = 2 * i + pr, ocol = 2 * jcol + pc;
            float v0 = fmaxf(acc[nt][0] + bv.x, 0.f);
            float v1 = fmaxf(acc[nt][1] + bv.y, 0.f);
            float v2 = fmaxf(acc[nt][2] + bv.z, 0.f);
            float v3 = fmaxf(acc[nt][3] + bv.w, 0.f);
            if constexpr (GRANOUT) {
                unsigned short h0 = bf16_rne(v0), h1 = bf16_rne(v1), h2 = bf16_rne(v2), h3 = bf16_rne(v3);
                unsigned short q0 = bf16_rne(v0 - bf16_tof(h0)), q1 = bf16_rne(v1 - bf16_tof(h1));
                unsigned short q2 = bf16_rne(v2 - bf16_tof(h2)), q3 = bf16_rne(v3 - bf16_tof(h3));
                int G = co0 >> 3, j0 = co0 & 7;
                size_t off = ((size_t)((b * (COUT / 8) + G) * (2 * H) + orow) * (2 * H) + ocol) * 8 + j0;
                *(uint2*)(goh + off) = make_uint2((unsigned)h0 | ((unsigned)h1 << 16),
                                                  (unsigned)h2 | ((unsigned)h3 << 16));
                *(uint2*)(gol + off) = make_uint2((unsigned)q0 | ((unsigned)q1 << 16),
                                                  (unsigned)q2 | ((unsigned)q3 << 16));
            } else {
                size_t ob = ((size_t)(b * COUT + co0) * (2 * H) + orow) * (2 * H) + ocol;
                constexpr size_t CS = (size_t)4 * H * H;
                outf[ob] = v0;
                outf[ob + CS] = v1;
                outf[ob + 2 * CS] = v2;
                outf[ob + 3 * CS] = v3;
            }
        }
    }
}

// ---------------- final conv (16->1) 3x3, 4 px per thread ----------------
__global__ void final_v2(const float* __restrict__ t2,  // (16,16,256,256)
                         const float* __restrict__ w,   // (1,16,3,3)
                         const float* __restrict__ bias,
                         float* __restrict__ out) {     // (16,1,256,256)
    int g = blockIdx.x * 256 + threadIdx.x;
    int pxb = g * 4;
    int b = pxb >> 16, p = pxb & 65535;
    int h = p >> 8, c0 = p & 255;
    const float* tb = t2 + (size_t)b * 16 * 65536;
    float acc[4];
    float bv = bias[0];
#pragma unroll
    for (int t = 0; t < 4; ++t) acc[t] = bv;
    for (int ci = 0; ci < 16; ++ci) {
        const float* pp = tb + (size_t)ci * 65536;
        const float* w9 = w + ci * 9;
        float win[3][6];
#pragma unroll
        for (int dr = 0; dr < 3; ++dr) {
            int rr = h - 1 + dr;
            bool vr = (rr >= 0 && rr < 256);
#pragma unroll
            for (int dc = 0; dc < 6; ++dc) {
                int cc = c0 - 1 + dc;
                win[dr][dc] = (vr && cc >= 0 && cc < 256) ? pp[rr * 256 + cc] : 0.f;
            }
        }
#pragma unroll
        for (int t = 0; t < 4; ++t)
#pragma unroll
            for (int dr = 0; dr < 3; ++dr)
#pragma unroll
                for (int dc = 0; dc < 3; ++dc)
                    acc[t] += win[dr][t + dc] * w9[dr * 3 + dc];
    }
    *(float4*)(out + pxb) = make_float4(acc[0], acc[1], acc[2], acc[3]);
}

// ---------------- launch ----------------
extern "C" void kernel_launch(void* const* d_in, const int* in_sizes, int n_in,
                              void* d_out, int out_size, void* d_ws, size_t ws_size,
                              hipStream_t stream) {
    (void)in_sizes; (void)n_in; (void)out_size; (void)ws_size;
    const float* x     = (const float*)d_in[0];
    const float* cw1   = (const float*)d_in[1];
    const float* cb1   = (const float*)d_in[2];
    const float* cw2   = (const float*)d_in[3];
    const float* cb2   = (const float*)d_in[4];
    const float* sw1   = (const float*)d_in[5];
    const float* sb1   = (const float*)d_in[6];
    const float* sw2   = (const float*)d_in[7];
    const float* sb2   = (const float*)d_in[8];
    const float* mkeys = (const float*)d_in[9];
    const float* mvals = (const float*)d_in[10];
    const float* mhard = (const float*)d_in[11];
    const float* dw1   = (const float*)d_in[12];
    const float* db1   = (const float*)d_in[13];
    const float* tw1   = (const float*)d_in[14];
    const float* tb1   = (const float*)d_in[15];
    const float* tw2   = (const float*)d_in[16];
    const float* tb2   = (const float*)d_in[17];
    const float* dw2   = (const float*)d_in[18];
    const float* db2   = (const float*)d_in[19];
    float* out = (float*)d_out;
    float* ws  = (float*)d_ws;

    const size_t OFF_KN  = 0;                   // knR: 800*128
    const size_t OFF_HN  = 102400;              // hn:  800*128
    const size_t OFF_C0  = 204800;              // c0 split: 2*128 shorts
    const size_t OFF_R14 = 204928;              // zc1 -> zs -> t1 granules
    const size_t OFF_R2  = OFF_R14 + 8388608;   // wse h/m/l + tconv prepped weights
    const size_t OFF_R3  = OFF_R2 + 8388608;    // zs1 -> d1 granules
    const size_t OFF_R5  = OFF_R3 + 4194304;    // dchh+dchl -> t2
    const size_t OFF_ZCQ = OFF_R5 + 16777216;   // zcq: 16*324*128
    const size_t OFF_HH  = OFF_ZCQ + 663552;    // hh
    const size_t OFF_HL  = OFF_HH + 51200;      // hl
    const size_t OFF_WH  = OFF_HL + 51200;      // wph
    const size_t OFF_WL  = OFF_WH + 73728;      // wpl
    const size_t OFF_HR  = OFF_WL + 73728;      // hardh+hardl (raw split): 102400 floats
    const size_t OFF_KNB = OFF_HR + 102400;     // knh+knl (norm key split): 102400 floats

    float* knR  = ws + OFF_KN;
    float* hn   = ws + OFF_HN;
    float* zc1  = ws + OFF_R14;
    float* zs   = ws + OFF_R14;
    float* zs1  = ws + OFF_R3;
    float* t2   = ws + OFF_R5;
    float* zcq  = ws + OFF_ZCQ;
    unsigned short* c0h  = (unsigned short*)(ws + OFF_C0);
    unsigned short* c0l  = c0h + 128;
    unsigned short* dchh = (unsigned short*)(ws + OFF_R5);   // 16*32*4096*8 shorts
    unsigned short* dchl = dchh + 16777216;
    unsigned short* hhp = (unsigned short*)(ws + OFF_HH);
    unsigned short* hlp = (unsigned short*)(ws + OFF_HL);
    unsigned short* wph = (unsigned short*)(ws + OFF_WH);
    unsigned short* wpl = (unsigned short*)(ws + OFF_WL);
    unsigned short* hardh = (unsigned short*)(ws + OFF_HR);          // 102400 shorts
    unsigned short* hardl = hardh + 102400;
    unsigned short* knh = (unsigned short*)(ws + OFF_KNB);           // 102400 shorts
    unsigned short* knl = knh + 102400;
    unsigned short* wseh = (unsigned short*)(ws + OFF_R2);           // 20480 shorts
    unsigned short* wsem = (unsigned short*)(ws + OFF_R2 + 10240);   // 20480 shorts
    unsigned short* wsel = (unsigned short*)(ws + OFF_R2 + 20480);   // 20480 shorts
    unsigned short* tw1h = (unsigned short*)(ws + OFF_R2 + 32768);   // 32768 shorts
    unsigned short* tw1l = tw1h + 32768;
    unsigned short* tw2h = tw1l + 32768;                             // 8192 shorts
    unsigned short* tw2l = tw2h + 8192;
    unsigned short* d1gh = (unsigned short*)(ws + OFF_R3);
    unsigned short* d1gl = d1gh + 4194304;
    unsigned short* t1gh = (unsigned short*)(ws + OFF_R14);
    unsigned short* t1gl = t1gh + 8388608;

    prep_norm_k<<<800, 128, 0, stream>>>(mkeys, mhard, knR, hn, hhp, hlp, hardh, hardl, knh, knl);
    prep_c0_k<<<1, 128, 0, stream>>>(mvals, c0h, c0l);
    prep_w1_k<<<576, 256, 0, stream>>>(dw1, wph, wpl);
    prep_wse_k<<<80, 256, 0, stream>>>(sw2, wseh, wsem, wsel);
    prep_tw<64, 32><<<128, 256, 0, stream>>>(tw1, tw1h, tw1l);
    prep_tw<32, 16><<<32, 256, 0, stream>>>(tw2, tw2h, tw2l);

    ce1_k<<<16 * 2 * 6, 256, 0, stream>>>(x, cw1, cb1, zc1);
    se1_k<<<16 * 64, 256, 0, stream>>>(x, sw1, sb1, zs1);
    ce2_v3<<<16 * 16, 256, 0, stream>>>(zc1, cw2, cb2, zcq);
    se2_mfma<<<16 * 64, 256, 0, stream>>>(zs1, wseh, wsem, wsel, sb2, zs);  // overwrites zc1 (dead)

    match_center_v3<<<324, 256, 0, stream>>>(zcq, knR, knh, knl, mvals, dchh, dchl);
    fill_c0_k<<<4096, 256, 0, stream>>>(c0h, c0l, dchh, dchl);
    match_skip_v7<<<16 * 64, 256, 0, stream>>>(zs, hn, hhp, hlp, hardh, hardl, dchh, dchl);

    dec1_v14<<<2048, 256, 0, stream>>>(dchh, dchl, wph, wpl, db1, d1gh, d1gl);  // overwrites zs1 (dead)

    tconv_m<64, 32, 64, false, true><<<16 * 64, 256, 0, stream>>>(
        d1gh, d1gl, tw1h, tw1l, tb1, nullptr, t1gh, t1gl);       // overwrites zs (dead)
    tconv_m<32, 16, 128, true, false><<<16 * 128, 256, 0, stream>>>(
        t1gh, t1gl, tw2h, tw2l, tb2, t2, nullptr, nullptr);      // overwrites dchh/dchl (dead)
    final_v2<<<1024, 256, 0, stream>>>(t2, dw2, db2, out);
}